// Round 1
// 687.840 us; speedup vs baseline: 1.1214x; 1.1214x over previous
//
#include <hip/hip_runtime.h>

// Problem constants (from reference setup_inputs)
#define F_IN 512
#define F1 64          // HEADS*HID = 8*8
#define NCLS 16
#define NEG_SLOPE 0.2f

typedef __attribute__((ext_vector_type(8))) short short8;
typedef __attribute__((ext_vector_type(4))) float f32x4;

__device__ __forceinline__ unsigned short f2bf(float f) {
    unsigned u = __float_as_uint(f);
    return (unsigned short)((u + 0x7fffu + ((u >> 16) & 1u)) >> 16);
}
__device__ __forceinline__ float bf2f(unsigned short u) {
    return __uint_as_float(((unsigned)u) << 16);
}

// ---------------- edge decode (int32 vs int64 robust) ----------------

__global__ __launch_bounds__(64) void k_detect(const int* __restrict__ ei, int E,
                                               unsigned* __restrict__ mode) {
    int t = threadIdx.x;
    unsigned nz = 0;
    int lim = (E > 256) ? 256 : E;
    for (int k = t; k < lim; k += 64) nz |= (unsigned)ei[2 * k + 1];
    for (int off = 1; off < 64; off <<= 1) nz |= __shfl_xor(nz, off);
    if (t == 0) *mode = (nz == 0) ? 1u : 0u;   // 1 = int64 layout
}

// ---------------- GEMM1 MFMA tile (bf16 in, fp32 acc) ----------------
// 64 rows x 64 cols per block, K=512 in chunks of 32. 4 waves; wave w owns
// rows w*16..w*16+15 as 4 MFMA 16x16 col-tiles. Fragment layouts (verified
// per guide §3): A[m=lane&15][k=quad*8+j]; B[k=quad*8+j][n=lane&15];
// C/D col=lane&15, row=quad*4+reg.

__device__ __forceinline__ void gemm1_tile(const float* __restrict__ x,
                                           const float* __restrict__ W1,
                                           const float* __restrict__ att_s,
                                           const float* __restrict__ att_d,
                                           unsigned short* __restrict__ h1b,
                                           float* __restrict__ a_s1,
                                           float* __restrict__ a_d1,
                                           int N, int row0,
                                           unsigned short (*Abuf)[40],
                                           unsigned short (*BbufT)[40]) {
    const int tid = threadIdx.x;
    const int w = tid >> 6, lane = tid & 63;
    const int quad = lane >> 4, r16 = lane & 15;

    f32x4 acc[4];
#pragma unroll
    for (int t = 0; t < 4; t++) acc[t] = (f32x4){0.f, 0.f, 0.f, 0.f};

    const int a_row = tid >> 2;             // 0..63
    const int a_seg = (tid & 3) * 8;        // 0,8,16,24
    const int b_col = tid & 63;             // 0..63
    const int b_kq  = tid >> 6;             // 0..3 (wave id)
    const int ar = row0 + a_row;

    for (int k0 = 0; k0 < F_IN; k0 += 32) {
        {
            float4 v0 = make_float4(0.f, 0.f, 0.f, 0.f), v1 = v0;
            if (ar < N) {
                const float* xp = x + (size_t)ar * F_IN + k0 + a_seg;
                v0 = *(const float4*)xp;
                v1 = *(const float4*)(xp + 4);
            }
            short8 cv;
            cv[0] = (short)f2bf(v0.x); cv[1] = (short)f2bf(v0.y);
            cv[2] = (short)f2bf(v0.z); cv[3] = (short)f2bf(v0.w);
            cv[4] = (short)f2bf(v1.x); cv[5] = (short)f2bf(v1.y);
            cv[6] = (short)f2bf(v1.z); cv[7] = (short)f2bf(v1.w);
            *(short8*)&Abuf[a_row][a_seg] = cv;
        }
        {
            const float* wp = W1 + (size_t)(k0 + b_kq * 8) * F1 + b_col;
            short8 cv;
#pragma unroll
            for (int j = 0; j < 8; j++)
                cv[j] = (short)f2bf(wp[(size_t)j * F1]);
            *(short8*)&BbufT[b_col][b_kq * 8] = cv;
        }
        __syncthreads();

        short8 af = *(const short8*)&Abuf[w * 16 + r16][quad * 8];
#pragma unroll
        for (int t = 0; t < 4; t++) {
            short8 bf = *(const short8*)&BbufT[t * 16 + r16][quad * 8];
            acc[t] = __builtin_amdgcn_mfma_f32_16x16x32_bf16(af, bf, acc[t], 0, 0, 0);
        }
        __syncthreads();
    }

    // epilogue
    float ats[4], atd[4];
#pragma unroll
    for (int t = 0; t < 4; t++) {
        ats[t] = att_s[t * 16 + r16];
        atd[t] = att_d[t * 16 + r16];
    }
#pragma unroll
    for (int r = 0; r < 4; r++) {
        int grow = row0 + w * 16 + quad * 4 + r;
        bool ok = grow < N;
        float ps[4], pd[4];
#pragma unroll
        for (int t = 0; t < 4; t++) {
            float vv = acc[t][r];
            if (ok) h1b[(size_t)grow * F1 + t * 16 + r16] = f2bf(vv);
            ps[t] = vv * ats[t];
            pd[t] = vv * atd[t];
        }
#pragma unroll
        for (int t = 0; t < 4; t++) {
            ps[t] += __shfl_xor(ps[t], 1); pd[t] += __shfl_xor(pd[t], 1);
            ps[t] += __shfl_xor(ps[t], 2); pd[t] += __shfl_xor(pd[t], 2);
            ps[t] += __shfl_xor(ps[t], 4); pd[t] += __shfl_xor(pd[t], 4);
        }
        if (ok && (r16 & 7) == 0) {
            int hh0 = r16 >> 3;   // 0 or 1
#pragma unroll
            for (int t = 0; t < 4; t++) {
                a_s1[(size_t)grow * 8 + t * 2 + hh0] = ps[t];
                a_d1[(size_t)grow * 8 + t * 2 + hh0] = pd[t];
            }
        }
    }
}

// ---------------- fused A: gemm1 (rows [0,rowSplit)) || edge decode + hists --
// Edge path: decode + clamp + per-node degree hist + LDS-aggregated coarse
// bucket hist (bucket = dst >> shift).

__global__ __launch_bounds__(256) void k_fusedA(const float* __restrict__ x,
                                                const float* __restrict__ W1,
                                                const float* __restrict__ att_s,
                                                const float* __restrict__ att_d,
                                                unsigned short* __restrict__ h1b,
                                                float* __restrict__ a_s1,
                                                float* __restrict__ a_d1, int N,
                                                const int* __restrict__ ei,
                                                const unsigned* __restrict__ mode,
                                                int* __restrict__ src32,
                                                int* __restrict__ dst32,
                                                unsigned* __restrict__ deg,
                                                unsigned* __restrict__ bucketCnt,
                                                int E, int ET, int nch,
                                                int nb, int shift) {
    __shared__ __align__(16) char smem[10240];
    unsigned b = blockIdx.x;
    if ((b & 1) == 0) {
        gemm1_tile(x, W1, att_s, att_d, h1b, a_s1, a_d1, N, (int)(b >> 1) * 64,
                   (unsigned short (*)[40])smem,
                   (unsigned short (*)[40])(smem + 5120));
        return;
    }
    unsigned* cntL = (unsigned*)smem;  // [1024]
    for (int i = threadIdx.x; i < 1024; i += 256) cntL[i] = 0u;
    __syncthreads();

    const unsigned stride = (unsigned)nch * 256u;
    unsigned t = (b >> 1) * 256u + threadIdx.x;
    bool m64 = (*mode != 0u);
    const long long* e64 = (const long long*)ei;
    unsigned i = t;
    for (; i + 3u * stride < (unsigned)ET; i += 4u * stride) {
        unsigned i0 = i, i1 = i + stride, i2 = i + 2u * stride, i3 = i + 3u * stride;
        int s0, v0, s1, v1, s2, v2, s3, v3;
        if (m64) {
            s0 = (int)e64[i0]; s1 = (int)e64[i1]; s2 = (int)e64[i2]; s3 = (int)e64[i3];
            v0 = (i0 < (unsigned)E) ? (int)e64[E + i0] : (int)(i0 - E);
            v1 = (i1 < (unsigned)E) ? (int)e64[E + i1] : (int)(i1 - E);
            v2 = (i2 < (unsigned)E) ? (int)e64[E + i2] : (int)(i2 - E);
            v3 = (i3 < (unsigned)E) ? (int)e64[E + i3] : (int)(i3 - E);
        } else {
            s0 = ei[i0]; s1 = ei[i1]; s2 = ei[i2]; s3 = ei[i3];
            v0 = (i0 < (unsigned)E) ? ei[E + i0] : (int)(i0 - E);
            v1 = (i1 < (unsigned)E) ? ei[E + i1] : (int)(i1 - E);
            v2 = (i2 < (unsigned)E) ? ei[E + i2] : (int)(i2 - E);
            v3 = (i3 < (unsigned)E) ? ei[E + i3] : (int)(i3 - E);
        }
        if (i0 >= (unsigned)E) s0 = (int)(i0 - E);
        if (i1 >= (unsigned)E) s1 = (int)(i1 - E);
        if (i2 >= (unsigned)E) s2 = (int)(i2 - E);
        if (i3 >= (unsigned)E) s3 = (int)(i3 - E);
        s0 = s0 < 0 ? 0 : (s0 >= N ? N - 1 : s0);  v0 = v0 < 0 ? 0 : (v0 >= N ? N - 1 : v0);
        s1 = s1 < 0 ? 0 : (s1 >= N ? N - 1 : s1);  v1 = v1 < 0 ? 0 : (v1 >= N ? N - 1 : v1);
        s2 = s2 < 0 ? 0 : (s2 >= N ? N - 1 : s2);  v2 = v2 < 0 ? 0 : (v2 >= N ? N - 1 : v2);
        s3 = s3 < 0 ? 0 : (s3 >= N ? N - 1 : s3);  v3 = v3 < 0 ? 0 : (v3 >= N ? N - 1 : v3);
        src32[i0] = s0; dst32[i0] = v0;
        src32[i1] = s1; dst32[i1] = v1;
        src32[i2] = s2; dst32[i2] = v2;
        src32[i3] = s3; dst32[i3] = v3;
        atomicAdd(&deg[v0], 1u);
        atomicAdd(&deg[v1], 1u);
        atomicAdd(&deg[v2], 1u);
        atomicAdd(&deg[v3], 1u);
        atomicAdd(&cntL[(unsigned)v0 >> shift], 1u);
        atomicAdd(&cntL[(unsigned)v1 >> shift], 1u);
        atomicAdd(&cntL[(unsigned)v2 >> shift], 1u);
        atomicAdd(&cntL[(unsigned)v3 >> shift], 1u);
    }
    for (; i < (unsigned)ET; i += stride) {
        int s, v;
        if (i < (unsigned)E) {
            if (m64) { s = (int)e64[i]; v = (int)e64[E + i]; }
            else     { s = ei[i];       v = ei[E + i]; }
        } else {
            s = v = (int)(i - E);
        }
        s = s < 0 ? 0 : (s >= N ? N - 1 : s);
        v = v < 0 ? 0 : (v >= N ? N - 1 : v);
        src32[i] = s; dst32[i] = v;
        atomicAdd(&deg[v], 1u);
        atomicAdd(&cntL[(unsigned)v >> shift], 1u);
    }
    __syncthreads();
    for (int k = threadIdx.x; k < nb; k += 256) {
        unsigned c = cntL[k];
        if (c) atomicAdd(&bucketCnt[k], c);
    }
}

// ---------------- fused B: gemm1 (rows [rowSplit,N)) || bucket scatter ------
// Edge path (pass1b): each block owns a CONTIGUOUS edge chunk. LDS count per
// bucket -> LDS scan -> one global atomicAdd per (block,bucket) reserves a
// PRIVATE contiguous span -> packed (src | local_dst<<20) records written into
// the private span. Private spans => L2 merges writes into full lines (no 16x
// HBM write amplification), and no per-edge dependent global atomic chain.

__global__ __launch_bounds__(256) void k_fusedB(const float* __restrict__ x,
                                                const float* __restrict__ W1,
                                                const float* __restrict__ att_s,
                                                const float* __restrict__ att_d,
                                                unsigned short* __restrict__ h1b,
                                                float* __restrict__ a_s1,
                                                float* __restrict__ a_d1, int N,
                                                int rowSplit,
                                                const int* __restrict__ src32,
                                                const int* __restrict__ dst32,
                                                unsigned* __restrict__ bucketFill,
                                                unsigned* __restrict__ pairs,
                                                int ET, int nch,
                                                int nb, int shift) {
    __shared__ __align__(16) char smem[10240];
    unsigned b = blockIdx.x;
    if (b & 1) {
        gemm1_tile(x, W1, att_s, att_d, h1b, a_s1, a_d1, N,
                   rowSplit + (int)(b >> 1) * 64,
                   (unsigned short (*)[40])smem,
                   (unsigned short (*)[40])(smem + 5120));
        return;
    }
    unsigned* cntA = (unsigned*)smem;           // [1024] counts -> span delta
    unsigned* ofsA = (unsigned*)(smem + 4096);  // [1024] local excl ofs -> cursor
    unsigned* part = (unsigned*)(smem + 8192);  // [256]
    const int t = threadIdx.x;
    const int chunk = (ET + nch - 1) / nch;
    const int cbase = (int)(b >> 1) * chunk;
    const int cend = (cbase + chunk < ET) ? cbase + chunk : ET;
    const unsigned lmask = (1u << shift) - 1u;

    for (int k = t; k < 1024; k += 256) cntA[k] = 0u;
    __syncthreads();
    // phase 1: count
    for (int k = cbase + t; k < cend; k += 256)
        atomicAdd(&cntA[(unsigned)dst32[k] >> shift], 1u);
    __syncthreads();
    // exclusive scan over 1024 entries (4 per thread)
    unsigned a0 = cntA[4 * t + 0], a1 = cntA[4 * t + 1];
    unsigned a2 = cntA[4 * t + 2], a3 = cntA[4 * t + 3];
    unsigned ssum = a0 + a1 + a2 + a3;
    part[t] = ssum;
    __syncthreads();
    for (int off = 1; off < 256; off <<= 1) {
        unsigned add = (t >= off) ? part[t - off] : 0u;
        __syncthreads();
        part[t] += add;
        __syncthreads();
    }
    unsigned excl = part[t] - ssum;
    ofsA[4 * t + 0] = excl;
    ofsA[4 * t + 1] = excl + a0;
    ofsA[4 * t + 2] = excl + a0 + a1;
    ofsA[4 * t + 3] = excl + a0 + a1 + a2;
    __syncthreads();
    // reserve private global spans; cntA becomes delta = globalBase - localOfs
    for (int k = t; k < nb; k += 256) {
        unsigned c = cntA[k];
        unsigned g = c ? atomicAdd(&bucketFill[k], c) : 0u;
        cntA[k] = g - ofsA[k];
    }
    __syncthreads();
    // phase 2: scatter packed records into private spans (ofsA = local cursor)
    for (int k = cbase + t; k < cend; k += 256) {
        int v = dst32[k];
        int s = src32[k];
        unsigned bb = (unsigned)v >> shift;
        unsigned slot = atomicAdd(&ofsA[bb], 1u);
        pairs[cntA[bb] + slot] = (unsigned)s | (((unsigned)v & lmask) << 20);
    }
}

// ---------------- CSR prefix-sum kernels ----------------

__global__ __launch_bounds__(256) void k_tilesum(const unsigned* __restrict__ deg,
                                                 int N, unsigned* __restrict__ tileSum) {
    int tid = threadIdx.x;
    int v = blockIdx.x * 256 + tid;
    unsigned d = (v < N) ? deg[v] : 0u;
    for (int off = 1; off < 64; off <<= 1) d += __shfl_xor(d, off);
    __shared__ unsigned ps[4];
    int lane = tid & 63, wid = tid >> 6;
    if (lane == 0) ps[wid] = d;
    __syncthreads();
    if (tid == 0) tileSum[blockIdx.x] = ps[0] + ps[1] + ps[2] + ps[3];
}

__global__ __launch_bounds__(1024) void k_scan_tiles(const unsigned* __restrict__ tileSum,
                                                     int nt, unsigned* __restrict__ tileOfs) {
    __shared__ unsigned sbuf[1024];
    int t = threadIdx.x;
    unsigned val = (t < nt) ? tileSum[t] : 0u;
    sbuf[t] = val;
    __syncthreads();
    for (int off = 1; off < 1024; off <<= 1) {
        unsigned add = (t >= off) ? sbuf[t - off] : 0u;
        __syncthreads();
        sbuf[t] += add;
        __syncthreads();
    }
    if (t < nt) tileOfs[t] = sbuf[t] - val;  // exclusive
}

__global__ __launch_bounds__(1024) void k_scan_buckets(const unsigned* __restrict__ bucketCnt,
                                                       int nb,
                                                       unsigned* __restrict__ bucketOfs,
                                                       unsigned* __restrict__ bucketFill) {
    __shared__ unsigned sbuf[1024];
    int t = threadIdx.x;
    unsigned val = (t < nb) ? bucketCnt[t] : 0u;
    sbuf[t] = val;
    __syncthreads();
    for (int off = 1; off < 1024; off <<= 1) {
        unsigned add = (t >= off) ? sbuf[t - off] : 0u;
        __syncthreads();
        sbuf[t] += add;
        __syncthreads();
    }
    if (t < nb) {
        unsigned e = sbuf[t] - val;  // exclusive
        bucketOfs[t] = e;
        bucketFill[t] = e;
    }
}

__global__ __launch_bounds__(256) void k_rowptr(const unsigned* __restrict__ deg,
                                                const unsigned* __restrict__ tileOfs,
                                                unsigned* __restrict__ row_ptr,
                                                int N, int ET) {
    __shared__ unsigned sbuf[256];
    int t = threadIdx.x;
    int v = blockIdx.x * 256 + t;
    unsigned d = (v < N) ? deg[v] : 0u;
    sbuf[t] = d;
    __syncthreads();
    for (int off = 1; off < 256; off <<= 1) {
        unsigned add = (t >= off) ? sbuf[t - off] : 0u;
        __syncthreads();
        sbuf[t] += add;
        __syncthreads();
    }
    if (v < N) row_ptr[v] = tileOfs[blockIdx.x] + sbuf[t] - d;
    if (blockIdx.x == 0 && t == 0) row_ptr[N] = (unsigned)ET;
}

// ---------------- bucket -> per-node CSR scatter ----------------
// One block per bucket. Only 1<<shift LDS fill counters (no capacity limit).
// ssrc writes land inside this bucket's private contiguous region (~deg*4 B),
// written by one block over a short window -> full-line L2 writebacks.

__global__ __launch_bounds__(256) void k_sort(const unsigned* __restrict__ pairs,
                                              const unsigned* __restrict__ bucketOfs,
                                              const unsigned* __restrict__ bucketCnt,
                                              const unsigned* __restrict__ row_ptr,
                                              unsigned* __restrict__ ssrc,
                                              int N, int shift) {
    __shared__ unsigned f[1024];
    __shared__ unsigned rbase[1024];
    const int b = blockIdx.x;
    const int t = threadIdx.x;
    const int nodes = 1 << shift;
    const int bbase = b << shift;
    for (int i = t; i < nodes; i += 256) {
        f[i] = 0u;
        int v = bbase + i;
        rbase[i] = (v < N) ? row_ptr[v] : 0u;
    }
    __syncthreads();
    const unsigned base = bucketOfs[b];
    const unsigned cnt = bucketCnt[b];
    for (unsigned i = (unsigned)t; i < cnt; i += 256u) {
        unsigned pk = pairs[base + i];
        unsigned s = pk & 0xFFFFFu;
        unsigned local = pk >> 20;
        unsigned pos = rbase[local] + atomicAdd(&f[local], 1u);
        ssrc[pos] = s;
    }
}

// ---------------- layer-1 aggregation: one wave per dst node ----------------
// Single-pass softmax; h1 gathered as bf16 (128B/edge/wave). lane = h*8+c.
// 8-deep batching to widen the dependent gather chain.

__global__ __launch_bounds__(256) void k_agg1(const unsigned short* __restrict__ h1b,
                                              const float* __restrict__ a_s1,
                                              const float* __restrict__ a_d1,
                                              const float* __restrict__ b1,
                                              const unsigned* __restrict__ row_ptr,
                                              const unsigned* __restrict__ ssrc,
                                              float* __restrict__ g, int N) {
    int wid = threadIdx.x >> 6, lane = threadIdx.x & 63;
    int v = blockIdx.x * 4 + wid;
    if (v >= N) return;
    unsigned base = row_ptr[v];
    unsigned deg = row_ptr[v + 1] - base;
    int h = lane >> 3;
    float adv = a_d1[(size_t)v * 8 + h];

    float denom = 0.f, acc = 0.f;
    unsigned j = 0;
    for (; j + 8 <= deg; j += 8) {
        unsigned s0 = ssrc[base + j + 0];
        unsigned s1 = ssrc[base + j + 1];
        unsigned s2 = ssrc[base + j + 2];
        unsigned s3 = ssrc[base + j + 3];
        unsigned s4 = ssrc[base + j + 4];
        unsigned s5 = ssrc[base + j + 5];
        unsigned s6 = ssrc[base + j + 6];
        unsigned s7 = ssrc[base + j + 7];
        float as0 = a_s1[(size_t)s0 * 8 + h];
        float as1 = a_s1[(size_t)s1 * 8 + h];
        float as2 = a_s1[(size_t)s2 * 8 + h];
        float as3 = a_s1[(size_t)s3 * 8 + h];
        float as4 = a_s1[(size_t)s4 * 8 + h];
        float as5 = a_s1[(size_t)s5 * 8 + h];
        float as6 = a_s1[(size_t)s6 * 8 + h];
        float as7 = a_s1[(size_t)s7 * 8 + h];
        float h0 = bf2f(h1b[(size_t)s0 * F1 + lane]);
        float h1 = bf2f(h1b[(size_t)s1 * F1 + lane]);
        float h2v = bf2f(h1b[(size_t)s2 * F1 + lane]);
        float h3 = bf2f(h1b[(size_t)s3 * F1 + lane]);
        float h4 = bf2f(h1b[(size_t)s4 * F1 + lane]);
        float h5 = bf2f(h1b[(size_t)s5 * F1 + lane]);
        float h6 = bf2f(h1b[(size_t)s6 * F1 + lane]);
        float h7 = bf2f(h1b[(size_t)s7 * F1 + lane]);
        float e0 = as0 + adv; e0 = e0 > 0.f ? e0 : NEG_SLOPE * e0; float p0 = __expf(e0);
        float e1 = as1 + adv; e1 = e1 > 0.f ? e1 : NEG_SLOPE * e1; float p1 = __expf(e1);
        float e2 = as2 + adv; e2 = e2 > 0.f ? e2 : NEG_SLOPE * e2; float p2 = __expf(e2);
        float e3 = as3 + adv; e3 = e3 > 0.f ? e3 : NEG_SLOPE * e3; float p3 = __expf(e3);
        float e4 = as4 + adv; e4 = e4 > 0.f ? e4 : NEG_SLOPE * e4; float p4 = __expf(e4);
        float e5 = as5 + adv; e5 = e5 > 0.f ? e5 : NEG_SLOPE * e5; float p5 = __expf(e5);
        float e6 = as6 + adv; e6 = e6 > 0.f ? e6 : NEG_SLOPE * e6; float p6 = __expf(e6);
        float e7 = as7 + adv; e7 = e7 > 0.f ? e7 : NEG_SLOPE * e7; float p7 = __expf(e7);
        denom += ((p0 + p1) + (p2 + p3)) + ((p4 + p5) + (p6 + p7));
        acc = fmaf(h0, p0, acc);
        acc = fmaf(h1, p1, acc);
        acc = fmaf(h2v, p2, acc);
        acc = fmaf(h3, p3, acc);
        acc = fmaf(h4, p4, acc);
        acc = fmaf(h5, p5, acc);
        acc = fmaf(h6, p6, acc);
        acc = fmaf(h7, p7, acc);
    }
    for (; j < deg; j++) {
        unsigned s = ssrc[base + j];
        float as = a_s1[(size_t)s * 8 + h];
        float hv = bf2f(h1b[(size_t)s * F1 + lane]);
        float e = as + adv; e = e > 0.f ? e : NEG_SLOPE * e;
        float p = __expf(e);
        denom += p;
        acc = fmaf(hv, p, acc);
    }
    float t = acc * (1.0f / denom) + b1[lane];
    g[(size_t)v * F1 + lane] = t > 0.f ? t : (__expf(t) - 1.f);  // ELU
}

// ---------------- GEMM2 + attention dots layer 2 ----------------

__global__ __launch_bounds__(256) void k_gemm2(const float* __restrict__ g,
                                               const float* __restrict__ W2,
                                               const float* __restrict__ as2w,
                                               const float* __restrict__ ad2w,
                                               float* __restrict__ h2,
                                               float* __restrict__ a_s2,
                                               float* __restrict__ a_d2, int N) {
    __shared__ float W2s[F1][NCLS];
    int tid = threadIdx.x;
    for (int i = tid; i < F1 * NCLS; i += 256) ((float*)W2s)[i] = W2[i];
    __syncthreads();
    int lane = tid & 63, wid = tid >> 6;
    int n = blockIdx.x * 16 + wid * 4 + (lane >> 4);
    int c = lane & 15;
    if (n >= N) return;
    float acc = 0.f;
#pragma unroll
    for (int k4 = 0; k4 < 16; k4++) {
        float4 gv = *(const float4*)(g + (size_t)n * F1 + k4 * 4);
        acc = fmaf(gv.x, W2s[k4 * 4 + 0][c], acc);
        acc = fmaf(gv.y, W2s[k4 * 4 + 1][c], acc);
        acc = fmaf(gv.z, W2s[k4 * 4 + 2][c], acc);
        acc = fmaf(gv.w, W2s[k4 * 4 + 3][c], acc);
    }
    h2[(size_t)n * NCLS + c] = acc;
    float s = acc * as2w[c];
    float d = acc * ad2w[c];
    s += __shfl_xor(s, 1); s += __shfl_xor(s, 2); s += __shfl_xor(s, 4); s += __shfl_xor(s, 8);
    d += __shfl_xor(d, 1); d += __shfl_xor(d, 2); d += __shfl_xor(d, 4); d += __shfl_xor(d, 8);
    if (c == 0) { a_s2[n] = s; a_d2[n] = d; }
}

// ---------------- layer-2 aggregation (single-pass) -> fp32 output ----------

__global__ __launch_bounds__(256) void k_agg2(const float* __restrict__ h2,
                                              const float* __restrict__ a_s2,
                                              const float* __restrict__ a_d2,
                                              const float* __restrict__ b2,
                                              const unsigned* __restrict__ row_ptr,
                                              const unsigned* __restrict__ ssrc,
                                              float* __restrict__ out, int N) {
    int wid = threadIdx.x >> 6, lane = threadIdx.x & 63;
    int v = blockIdx.x * 4 + wid;
    if (v >= N) return;
    unsigned base = row_ptr[v];
    unsigned deg = row_ptr[v + 1] - base;
    float adv = a_d2[v];
    int sub = lane >> 4, c = lane & 15;

    float denom = 0.f, acc = 0.f;
    unsigned j = sub;
    for (; j + 12 < deg; j += 16) {
        unsigned s0 = ssrc[base + j + 0];
        unsigned s1 = ssrc[base + j + 4];
        unsigned s2 = ssrc[base + j + 8];
        unsigned s3 = ssrc[base + j + 12];
        float as0 = a_s2[s0];
        float as1 = a_s2[s1];
        float as2 = a_s2[s2];
        float as3 = a_s2[s3];
        float h0 = h2[(size_t)s0 * NCLS + c];
        float h1v = h2[(size_t)s1 * NCLS + c];
        float h2v = h2[(size_t)s2 * NCLS + c];
        float h3 = h2[(size_t)s3 * NCLS + c];
        float e0 = as0 + adv; e0 = e0 > 0.f ? e0 : NEG_SLOPE * e0; float p0 = __expf(e0);
        float e1 = as1 + adv; e1 = e1 > 0.f ? e1 : NEG_SLOPE * e1; float p1 = __expf(e1);
        float e2 = as2 + adv; e2 = e2 > 0.f ? e2 : NEG_SLOPE * e2; float p2 = __expf(e2);
        float e3 = as3 + adv; e3 = e3 > 0.f ? e3 : NEG_SLOPE * e3; float p3 = __expf(e3);
        denom += (p0 + p1) + (p2 + p3);
        acc = fmaf(h0, p0, acc);
        acc = fmaf(h1v, p1, acc);
        acc = fmaf(h2v, p2, acc);
        acc = fmaf(h3, p3, acc);
    }
    for (; j < deg; j += 4) {
        unsigned s = ssrc[base + j];
        float as = a_s2[s];
        float hv = h2[(size_t)s * NCLS + c];
        float e = as + adv; e = e > 0.f ? e : NEG_SLOPE * e;
        float p = __expf(e);
        denom += p;
        acc = fmaf(hv, p, acc);
    }
    acc += __shfl_xor(acc, 16);
    acc += __shfl_xor(acc, 32);
    denom += __shfl_xor(denom, 16);
    denom += __shfl_xor(denom, 32);
    if (lane < 16) {
        out[(size_t)v * NCLS + c] = acc * (1.0f / denom) + b2[c];
    }
}

// ---------------- launch ----------------

static inline size_t algn(size_t x) { return (x + 255) & ~(size_t)255; }

extern "C" void kernel_launch(void* const* d_in, const int* in_sizes, int n_in,
                              void* d_out, int out_size, void* d_ws, size_t ws_size,
                              hipStream_t stream) {
    const float* x   = (const float*)d_in[0];
    const int* ei    = (const int*)d_in[1];
    const float* W1  = (const float*)d_in[2];
    const float* as1 = (const float*)d_in[3];
    const float* ad1 = (const float*)d_in[4];
    const float* b1  = (const float*)d_in[5];
    const float* W2  = (const float*)d_in[6];
    const float* as2 = (const float*)d_in[7];
    const float* ad2 = (const float*)d_in[8];
    const float* b2  = (const float*)d_in[9];

    const int N = in_sizes[0] / F_IN;
    const int E = in_sizes[1] / 2;
    const int ET = E + N;
    const int nt = (N + 255) / 256;   // scan tiles (<= 1024)

    // coarse buckets for the CSR sort (nodes-per-bucket = 1<<shift, nb <= 1024)
    int shift = 8;
    int nb = (N + 255) >> 8;
    while (nb > 1024) { shift++; nb = (N + (1 << shift) - 1) >> shift; }

    const int GA_T = ((N / 2) + 63) / 64;       // gemm tiles in half A
    const int rowSplit = GA_T * 64;
    const int GB_T = (N - rowSplit + 63) / 64;  // gemm tiles in half B

    char* p = (char*)d_ws;
    unsigned short* h1b = (unsigned short*)p;  p += algn((size_t)N * F1 * 2);
    float* g    = (float*)p;      p += algn((size_t)N * F1 * 4);
    float* a_s1 = (float*)p;      p += algn((size_t)N * 8 * 4);
    float* a_d1 = (float*)p;      p += algn((size_t)N * 8 * 4);
    float* h2   = (float*)p;      p += algn((size_t)N * NCLS * 4);
    float* a_s2 = (float*)p;      p += algn((size_t)N * 4);
    float* a_d2 = (float*)p;      p += algn((size_t)N * 4);
    unsigned* deg     = (unsigned*)p;  p += algn((size_t)N * 4);
    unsigned* row_ptr = (unsigned*)p;  p += algn((size_t)(N + 1) * 4);
    unsigned* tileSum = (unsigned*)p;  p += algn((size_t)1024 * 4);
    unsigned* tileOfs = (unsigned*)p;  p += algn((size_t)1024 * 4);
    unsigned* bucketCnt  = (unsigned*)p;  p += algn((size_t)1024 * 4);
    unsigned* bucketOfs  = (unsigned*)p;  p += algn((size_t)1024 * 4);
    unsigned* bucketFill = (unsigned*)p;  p += algn((size_t)1024 * 4);
    unsigned* mode    = (unsigned*)p;  p += algn(256);
    int* src32 = (int*)p;              p += algn((size_t)ET * 4);
    int* dst32 = (int*)p;              p += algn((size_t)ET * 4);
    unsigned* ssrc = (unsigned*)p;     p += algn((size_t)ET * 4);
    // pairs[] lifetime (fusedB -> k_sort) is disjoint from g[] (agg1 -> gemm2):
    // alias to save workspace. ET*4 (13.2 MB) <= N*F1*4 (25.6 MB).
    unsigned* pairs = (unsigned*)g;

    hipMemsetAsync(deg, 0, (size_t)N * 4, stream);
    hipMemsetAsync(bucketCnt, 0, (size_t)nb * 4, stream);

    dim3 b256(256);
    k_detect<<<dim3(1), dim3(64), 0, stream>>>(ei, E, mode);

    // A: gemm rows [0,rowSplit) interleaved with edge decode + histograms
    k_fusedA<<<dim3(2 * GA_T), b256, 0, stream>>>(x, W1, as1, ad1, h1b, a_s1, a_d1, N,
                                                  ei, mode, src32, dst32, deg, bucketCnt,
                                                  E, ET, GA_T, nb, shift);

    k_tilesum<<<dim3(nt), b256, 0, stream>>>(deg, N, tileSum);
    k_scan_tiles<<<dim3(1), dim3(1024), 0, stream>>>(tileSum, nt, tileOfs);
    k_rowptr<<<dim3(nt), b256, 0, stream>>>(deg, tileOfs, row_ptr, N, ET);
    k_scan_buckets<<<dim3(1), dim3(1024), 0, stream>>>(bucketCnt, nb, bucketOfs, bucketFill);

    // B: gemm rows [rowSplit,N) interleaved with bucket scatter (pass1b)
    k_fusedB<<<dim3(2 * GB_T), b256, 0, stream>>>(x, W1, as1, ad1, h1b, a_s1, a_d1, N,
                                                  rowSplit, src32, dst32, bucketFill,
                                                  pairs, ET, GB_T, nb, shift);

    // bucket -> per-node CSR
    k_sort<<<dim3(nb), b256, 0, stream>>>(pairs, bucketOfs, bucketCnt, row_ptr, ssrc, N, shift);

    k_agg1<<<dim3((N + 3) / 4), b256, 0, stream>>>(h1b, a_s1, a_d1, b1, row_ptr, ssrc, g, N);
    k_gemm2<<<dim3((N + 15) / 16), b256, 0, stream>>>(g, W2, as2, ad2, h2, a_s2, a_d2, N);
    k_agg2<<<dim3((N + 3) / 4), b256, 0, stream>>>(h2, a_s2, a_d2, b2, row_ptr, ssrc,
                                                   (float*)d_out, N);
}

// Round 2
// 640.226 us; speedup vs baseline: 1.2049x; 1.0744x over previous
//
#include <hip/hip_runtime.h>

// Problem constants (from reference setup_inputs)
#define F_IN 512
#define F1 64          // HEADS*HID = 8*8
#define NCLS 16
#define NEG_SLOPE 0.2f

typedef __attribute__((ext_vector_type(8))) short short8;
typedef __attribute__((ext_vector_type(4))) float f32x4;

__device__ __forceinline__ unsigned short f2bf(float f) {
    unsigned u = __float_as_uint(f);
    return (unsigned short)((u + 0x7fffu + ((u >> 16) & 1u)) >> 16);
}
__device__ __forceinline__ float bf2f(unsigned short u) {
    return __uint_as_float(((unsigned)u) << 16);
}

// ---------------- edge decode (int32 vs int64 robust) ----------------

__global__ __launch_bounds__(64) void k_detect(const int* __restrict__ ei, int E,
                                               unsigned* __restrict__ mode) {
    int t = threadIdx.x;
    unsigned nz = 0;
    int lim = (E > 256) ? 256 : E;
    for (int k = t; k < lim; k += 64) nz |= (unsigned)ei[2 * k + 1];
    for (int off = 1; off < 64; off <<= 1) nz |= __shfl_xor(nz, off);
    if (t == 0) *mode = (nz == 0) ? 1u : 0u;   // 1 = int64 layout
}

__device__ __forceinline__ void decode_edge(const int* __restrict__ ei,
                                            const long long* __restrict__ e64,
                                            bool m64, unsigned i, int E, int N,
                                            int& s, int& v) {
    if (i < (unsigned)E) {
        if (m64) { s = (int)e64[i]; v = (int)e64[E + i]; }
        else     { s = ei[i];       v = ei[E + i]; }
    } else {
        s = (int)(i - (unsigned)E);
        v = s;
    }
    s = s < 0 ? 0 : (s >= N ? N - 1 : s);
    v = v < 0 ? 0 : (v >= N ? N - 1 : v);
}

__device__ __forceinline__ int decode_dst(const int* __restrict__ ei,
                                          const long long* __restrict__ e64,
                                          bool m64, unsigned i, int E, int N) {
    int v;
    if (i < (unsigned)E) v = m64 ? (int)e64[E + i] : ei[E + i];
    else                 v = (int)(i - (unsigned)E);
    return v < 0 ? 0 : (v >= N ? N - 1 : v);
}

// ---------------- GEMM1 MFMA tile (bf16 in, fp32 acc) ----------------
// 64 rows x 64 cols per block, K=512 in chunks of 32. 4 waves; wave w owns
// rows w*16..w*16+15 as 4 MFMA 16x16 col-tiles. Fragment layouts (verified
// per guide §3): A[m=lane&15][k=quad*8+j]; B[k=quad*8+j][n=lane&15];
// C/D col=lane&15, row=quad*4+reg.

__device__ __forceinline__ void gemm1_tile(const float* __restrict__ x,
                                           const float* __restrict__ W1,
                                           const float* __restrict__ att_s,
                                           const float* __restrict__ att_d,
                                           unsigned short* __restrict__ h1b,
                                           float* __restrict__ a_s1,
                                           float* __restrict__ a_d1,
                                           int N, int row0,
                                           unsigned short (*Abuf)[40],
                                           unsigned short (*BbufT)[40]) {
    const int tid = threadIdx.x;
    const int w = tid >> 6, lane = tid & 63;
    const int quad = lane >> 4, r16 = lane & 15;

    f32x4 acc[4];
#pragma unroll
    for (int t = 0; t < 4; t++) acc[t] = (f32x4){0.f, 0.f, 0.f, 0.f};

    const int a_row = tid >> 2;             // 0..63
    const int a_seg = (tid & 3) * 8;        // 0,8,16,24
    const int b_col = tid & 63;             // 0..63
    const int b_kq  = tid >> 6;             // 0..3 (wave id)
    const int ar = row0 + a_row;

    for (int k0 = 0; k0 < F_IN; k0 += 32) {
        {
            float4 v0 = make_float4(0.f, 0.f, 0.f, 0.f), v1 = v0;
            if (ar < N) {
                const float* xp = x + (size_t)ar * F_IN + k0 + a_seg;
                v0 = *(const float4*)xp;
                v1 = *(const float4*)(xp + 4);
            }
            short8 cv;
            cv[0] = (short)f2bf(v0.x); cv[1] = (short)f2bf(v0.y);
            cv[2] = (short)f2bf(v0.z); cv[3] = (short)f2bf(v0.w);
            cv[4] = (short)f2bf(v1.x); cv[5] = (short)f2bf(v1.y);
            cv[6] = (short)f2bf(v1.z); cv[7] = (short)f2bf(v1.w);
            *(short8*)&Abuf[a_row][a_seg] = cv;
        }
        {
            const float* wp = W1 + (size_t)(k0 + b_kq * 8) * F1 + b_col;
            short8 cv;
#pragma unroll
            for (int j = 0; j < 8; j++)
                cv[j] = (short)f2bf(wp[(size_t)j * F1]);
            *(short8*)&BbufT[b_col][b_kq * 8] = cv;
        }
        __syncthreads();

        short8 af = *(const short8*)&Abuf[w * 16 + r16][quad * 8];
#pragma unroll
        for (int t = 0; t < 4; t++) {
            short8 bf = *(const short8*)&BbufT[t * 16 + r16][quad * 8];
            acc[t] = __builtin_amdgcn_mfma_f32_16x16x32_bf16(af, bf, acc[t], 0, 0, 0);
        }
        __syncthreads();
    }

    // epilogue
    float ats[4], atd[4];
#pragma unroll
    for (int t = 0; t < 4; t++) {
        ats[t] = att_s[t * 16 + r16];
        atd[t] = att_d[t * 16 + r16];
    }
#pragma unroll
    for (int r = 0; r < 4; r++) {
        int grow = row0 + w * 16 + quad * 4 + r;
        bool ok = grow < N;
        float ps[4], pd[4];
#pragma unroll
        for (int t = 0; t < 4; t++) {
            float vv = acc[t][r];
            if (ok) h1b[(size_t)grow * F1 + t * 16 + r16] = f2bf(vv);
            ps[t] = vv * ats[t];
            pd[t] = vv * atd[t];
        }
#pragma unroll
        for (int t = 0; t < 4; t++) {
            ps[t] += __shfl_xor(ps[t], 1); pd[t] += __shfl_xor(pd[t], 1);
            ps[t] += __shfl_xor(ps[t], 2); pd[t] += __shfl_xor(pd[t], 2);
            ps[t] += __shfl_xor(ps[t], 4); pd[t] += __shfl_xor(pd[t], 4);
        }
        if (ok && (r16 & 7) == 0) {
            int hh0 = r16 >> 3;   // 0 or 1
#pragma unroll
            for (int t = 0; t < 4; t++) {
                a_s1[(size_t)grow * 8 + t * 2 + hh0] = ps[t];
                a_d1[(size_t)grow * 8 + t * 2 + hh0] = pd[t];
            }
        }
    }
}

// ---------------- fused A: gemm1 (rows [0,rowSplit)) || bucket histogram ----
// Edge path: decode dst only + LDS-aggregated coarse bucket hist
// (bucket = dst >> shift). No per-node atomics, no src32/dst32 stream.

__global__ __launch_bounds__(256) void k_fusedA(const float* __restrict__ x,
                                                const float* __restrict__ W1,
                                                const float* __restrict__ att_s,
                                                const float* __restrict__ att_d,
                                                unsigned short* __restrict__ h1b,
                                                float* __restrict__ a_s1,
                                                float* __restrict__ a_d1, int N,
                                                const int* __restrict__ ei,
                                                const unsigned* __restrict__ mode,
                                                unsigned* __restrict__ bucketCnt,
                                                int E, int ET, int nch,
                                                int nb, int shift) {
    __shared__ __align__(16) char smem[10240];
    unsigned b = blockIdx.x;
    if ((b & 1) == 0) {
        gemm1_tile(x, W1, att_s, att_d, h1b, a_s1, a_d1, N, (int)(b >> 1) * 64,
                   (unsigned short (*)[40])smem,
                   (unsigned short (*)[40])(smem + 5120));
        return;
    }
    unsigned* cntL = (unsigned*)smem;  // [1024]
    for (int i = threadIdx.x; i < 1024; i += 256) cntL[i] = 0u;
    __syncthreads();

    const unsigned stride = (unsigned)nch * 256u;
    bool m64 = (*mode != 0u);
    const long long* e64 = (const long long*)ei;
    unsigned i = (b >> 1) * 256u + threadIdx.x;
    for (; i + 3u * stride < (unsigned)ET; i += 4u * stride) {
        int v0 = decode_dst(ei, e64, m64, i, E, N);
        int v1 = decode_dst(ei, e64, m64, i + stride, E, N);
        int v2 = decode_dst(ei, e64, m64, i + 2u * stride, E, N);
        int v3 = decode_dst(ei, e64, m64, i + 3u * stride, E, N);
        atomicAdd(&cntL[(unsigned)v0 >> shift], 1u);
        atomicAdd(&cntL[(unsigned)v1 >> shift], 1u);
        atomicAdd(&cntL[(unsigned)v2 >> shift], 1u);
        atomicAdd(&cntL[(unsigned)v3 >> shift], 1u);
    }
    for (; i < (unsigned)ET; i += stride) {
        int v = decode_dst(ei, e64, m64, i, E, N);
        atomicAdd(&cntL[(unsigned)v >> shift], 1u);
    }
    __syncthreads();
    for (int k = threadIdx.x; k < nb; k += 256) {
        unsigned c = cntL[k];
        if (c) atomicAdd(&bucketCnt[k], c);
    }
}

// ---------------- fused B: gemm1 (rows [rowSplit,N)) || bucket scatter ------
// Edge path: each block owns a CONTIGUOUS edge chunk, re-decoded from ei.
// LDS count per bucket -> LDS scan -> one global atomicAdd per (block,bucket)
// reserves a PRIVATE contiguous span -> packed (src | local_dst<<20) records
// written into the private span. Private spans => L2 merges writes into full
// lines, no per-edge dependent global atomic chain.

__global__ __launch_bounds__(256) void k_fusedB(const float* __restrict__ x,
                                                const float* __restrict__ W1,
                                                const float* __restrict__ att_s,
                                                const float* __restrict__ att_d,
                                                unsigned short* __restrict__ h1b,
                                                float* __restrict__ a_s1,
                                                float* __restrict__ a_d1, int N,
                                                int rowSplit,
                                                const int* __restrict__ ei,
                                                const unsigned* __restrict__ mode,
                                                unsigned* __restrict__ bucketFill,
                                                unsigned* __restrict__ pairs,
                                                int E, int ET, int nch,
                                                int nb, int shift) {
    __shared__ __align__(16) char smem[10240];
    unsigned b = blockIdx.x;
    if (b & 1) {
        gemm1_tile(x, W1, att_s, att_d, h1b, a_s1, a_d1, N,
                   rowSplit + (int)(b >> 1) * 64,
                   (unsigned short (*)[40])smem,
                   (unsigned short (*)[40])(smem + 5120));
        return;
    }
    unsigned* cntA = (unsigned*)smem;           // [1024] counts -> span delta
    unsigned* ofsA = (unsigned*)(smem + 4096);  // [1024] local excl ofs -> cursor
    unsigned* part = (unsigned*)(smem + 8192);  // [256]
    const int t = threadIdx.x;
    const int chunk = (ET + nch - 1) / nch;
    const int cbase = (int)(b >> 1) * chunk;
    const int cend = (cbase + chunk < ET) ? cbase + chunk : ET;
    const unsigned lmask = (1u << shift) - 1u;
    bool m64 = (*mode != 0u);
    const long long* e64 = (const long long*)ei;

    for (int k = t; k < 1024; k += 256) cntA[k] = 0u;
    __syncthreads();
    // phase 1: count (decode dst only)
    for (int k = cbase + t; k < cend; k += 256) {
        int v = decode_dst(ei, e64, m64, (unsigned)k, E, N);
        atomicAdd(&cntA[(unsigned)v >> shift], 1u);
    }
    __syncthreads();
    // exclusive scan over 1024 entries (4 per thread)
    unsigned a0 = cntA[4 * t + 0], a1 = cntA[4 * t + 1];
    unsigned a2 = cntA[4 * t + 2], a3 = cntA[4 * t + 3];
    unsigned ssum = a0 + a1 + a2 + a3;
    part[t] = ssum;
    __syncthreads();
    for (int off = 1; off < 256; off <<= 1) {
        unsigned add = (t >= off) ? part[t - off] : 0u;
        __syncthreads();
        part[t] += add;
        __syncthreads();
    }
    unsigned excl = part[t] - ssum;
    ofsA[4 * t + 0] = excl;
    ofsA[4 * t + 1] = excl + a0;
    ofsA[4 * t + 2] = excl + a0 + a1;
    ofsA[4 * t + 3] = excl + a0 + a1 + a2;
    __syncthreads();
    // reserve private global spans; cntA becomes delta = globalBase - localOfs
    for (int k = t; k < nb; k += 256) {
        unsigned c = cntA[k];
        unsigned g = c ? atomicAdd(&bucketFill[k], c) : 0u;
        cntA[k] = g - ofsA[k];
    }
    __syncthreads();
    // phase 2: re-decode and scatter packed records into private spans
    for (int k = cbase + t; k < cend; k += 256) {
        int s, v;
        decode_edge(ei, e64, m64, (unsigned)k, E, N, s, v);
        unsigned bb = (unsigned)v >> shift;
        unsigned slot = atomicAdd(&ofsA[bb], 1u);
        pairs[cntA[bb] + slot] = (unsigned)s | (((unsigned)v & lmask) << 20);
    }
}

// ---------------- bucket scan (global CSR offsets at bucket granularity) ----

__global__ __launch_bounds__(1024) void k_scan_buckets(const unsigned* __restrict__ bucketCnt,
                                                       int nb, int ET,
                                                       unsigned* __restrict__ bucketOfs,
                                                       unsigned* __restrict__ bucketFill,
                                                       unsigned* __restrict__ row_ptr,
                                                       int N) {
    __shared__ unsigned sbuf[1024];
    int t = threadIdx.x;
    unsigned val = (t < nb) ? bucketCnt[t] : 0u;
    sbuf[t] = val;
    __syncthreads();
    for (int off = 1; off < 1024; off <<= 1) {
        unsigned add = (t >= off) ? sbuf[t - off] : 0u;
        __syncthreads();
        sbuf[t] += add;
        __syncthreads();
    }
    if (t < nb) {
        unsigned e = sbuf[t] - val;  // exclusive
        bucketOfs[t] = e;
        bucketFill[t] = e;
    }
    if (t == 0) row_ptr[N] = (unsigned)ET;
}

// ---------------- bucket -> per-node CSR scatter (+ row_ptr build) ----------
// One block per bucket. Pass 1: count per-node degrees in LDS. Block scan ->
// row_ptr[v] (bucketOfs[b] == row_ptr[bucket_base] since bucket regions are
// contiguous node ranges). Pass 2: scatter with LDS cursors. ssrc writes land
// inside this bucket's private contiguous region -> full-line L2 writebacks.

__global__ __launch_bounds__(256) void k_sort(const unsigned* __restrict__ pairs,
                                              const unsigned* __restrict__ bucketOfs,
                                              const unsigned* __restrict__ bucketCnt,
                                              unsigned* __restrict__ row_ptr,
                                              unsigned* __restrict__ ssrc,
                                              int N, int shift) {
    __shared__ unsigned f[1024];      // counts -> cursors
    __shared__ unsigned part[256];
    const int b = blockIdx.x;
    const int t = threadIdx.x;
    const int nodes = 1 << shift;     // <= 1024
    const int bbase = b << shift;
    for (int i = t; i < 1024; i += 256) f[i] = 0u;
    __syncthreads();
    const unsigned base = bucketOfs[b];
    const unsigned cnt = bucketCnt[b];
    // pass 1: per-node degree count
    for (unsigned i = (unsigned)t; i < cnt; i += 256u)
        atomicAdd(&f[pairs[base + i] >> 20], 1u);
    __syncthreads();
    // block exclusive scan over 1024 entries (4 per thread)
    unsigned a0 = f[4 * t + 0], a1 = f[4 * t + 1];
    unsigned a2 = f[4 * t + 2], a3 = f[4 * t + 3];
    unsigned ssum = a0 + a1 + a2 + a3;
    part[t] = ssum;
    __syncthreads();
    for (int off = 1; off < 256; off <<= 1) {
        unsigned add = (t >= off) ? part[t - off] : 0u;
        __syncthreads();
        part[t] += add;
        __syncthreads();
    }
    unsigned excl = part[t] - ssum;
    // write row_ptr + init cursors (f reads for scan all happened pre-barrier)
    unsigned c0 = base + excl;
    unsigned c1 = c0 + a0;
    unsigned c2 = c1 + a1;
    unsigned c3 = c2 + a2;
    {
        int v0 = bbase + 4 * t;
        if (v0 + 0 < N && 4 * t + 0 < nodes) row_ptr[v0 + 0] = c0;
        if (v0 + 1 < N && 4 * t + 1 < nodes) row_ptr[v0 + 1] = c1;
        if (v0 + 2 < N && 4 * t + 2 < nodes) row_ptr[v0 + 2] = c2;
        if (v0 + 3 < N && 4 * t + 3 < nodes) row_ptr[v0 + 3] = c3;
    }
    f[4 * t + 0] = c0;
    f[4 * t + 1] = c1;
    f[4 * t + 2] = c2;
    f[4 * t + 3] = c3;
    __syncthreads();
    // pass 2: scatter
    for (unsigned i = (unsigned)t; i < cnt; i += 256u) {
        unsigned pk = pairs[base + i];
        unsigned local = pk >> 20;
        unsigned pos = atomicAdd(&f[local], 1u);
        ssrc[pos] = pk & 0xFFFFFu;
    }
}

// ---------------- layer-1 aggregation: one wave per dst node ----------------
// Single-pass softmax; h1 gathered as bf16 (128B/edge/wave). lane = h*8+c.
// 8-deep batching to widen the dependent gather chain.

__global__ __launch_bounds__(256) void k_agg1(const unsigned short* __restrict__ h1b,
                                              const float* __restrict__ a_s1,
                                              const float* __restrict__ a_d1,
                                              const float* __restrict__ b1,
                                              const unsigned* __restrict__ row_ptr,
                                              const unsigned* __restrict__ ssrc,
                                              float* __restrict__ g, int N) {
    int wid = threadIdx.x >> 6, lane = threadIdx.x & 63;
    int v = blockIdx.x * 4 + wid;
    if (v >= N) return;
    unsigned base = row_ptr[v];
    unsigned deg = row_ptr[v + 1] - base;
    int h = lane >> 3;
    float adv = a_d1[(size_t)v * 8 + h];

    float denom = 0.f, acc = 0.f;
    unsigned j = 0;
    for (; j + 8 <= deg; j += 8) {
        unsigned s0 = ssrc[base + j + 0];
        unsigned s1 = ssrc[base + j + 1];
        unsigned s2 = ssrc[base + j + 2];
        unsigned s3 = ssrc[base + j + 3];
        unsigned s4 = ssrc[base + j + 4];
        unsigned s5 = ssrc[base + j + 5];
        unsigned s6 = ssrc[base + j + 6];
        unsigned s7 = ssrc[base + j + 7];
        float as0 = a_s1[(size_t)s0 * 8 + h];
        float as1 = a_s1[(size_t)s1 * 8 + h];
        float as2 = a_s1[(size_t)s2 * 8 + h];
        float as3 = a_s1[(size_t)s3 * 8 + h];
        float as4 = a_s1[(size_t)s4 * 8 + h];
        float as5 = a_s1[(size_t)s5 * 8 + h];
        float as6 = a_s1[(size_t)s6 * 8 + h];
        float as7 = a_s1[(size_t)s7 * 8 + h];
        float h0 = bf2f(h1b[(size_t)s0 * F1 + lane]);
        float h1 = bf2f(h1b[(size_t)s1 * F1 + lane]);
        float h2v = bf2f(h1b[(size_t)s2 * F1 + lane]);
        float h3 = bf2f(h1b[(size_t)s3 * F1 + lane]);
        float h4 = bf2f(h1b[(size_t)s4 * F1 + lane]);
        float h5 = bf2f(h1b[(size_t)s5 * F1 + lane]);
        float h6 = bf2f(h1b[(size_t)s6 * F1 + lane]);
        float h7 = bf2f(h1b[(size_t)s7 * F1 + lane]);
        float e0 = as0 + adv; e0 = e0 > 0.f ? e0 : NEG_SLOPE * e0; float p0 = __expf(e0);
        float e1 = as1 + adv; e1 = e1 > 0.f ? e1 : NEG_SLOPE * e1; float p1 = __expf(e1);
        float e2 = as2 + adv; e2 = e2 > 0.f ? e2 : NEG_SLOPE * e2; float p2 = __expf(e2);
        float e3 = as3 + adv; e3 = e3 > 0.f ? e3 : NEG_SLOPE * e3; float p3 = __expf(e3);
        float e4 = as4 + adv; e4 = e4 > 0.f ? e4 : NEG_SLOPE * e4; float p4 = __expf(e4);
        float e5 = as5 + adv; e5 = e5 > 0.f ? e5 : NEG_SLOPE * e5; float p5 = __expf(e5);
        float e6 = as6 + adv; e6 = e6 > 0.f ? e6 : NEG_SLOPE * e6; float p6 = __expf(e6);
        float e7 = as7 + adv; e7 = e7 > 0.f ? e7 : NEG_SLOPE * e7; float p7 = __expf(e7);
        denom += ((p0 + p1) + (p2 + p3)) + ((p4 + p5) + (p6 + p7));
        acc = fmaf(h0, p0, acc);
        acc = fmaf(h1, p1, acc);
        acc = fmaf(h2v, p2, acc);
        acc = fmaf(h3, p3, acc);
        acc = fmaf(h4, p4, acc);
        acc = fmaf(h5, p5, acc);
        acc = fmaf(h6, p6, acc);
        acc = fmaf(h7, p7, acc);
    }
    for (; j < deg; j++) {
        unsigned s = ssrc[base + j];
        float as = a_s1[(size_t)s * 8 + h];
        float hv = bf2f(h1b[(size_t)s * F1 + lane]);
        float e = as + adv; e = e > 0.f ? e : NEG_SLOPE * e;
        float p = __expf(e);
        denom += p;
        acc = fmaf(hv, p, acc);
    }
    float t = acc * (1.0f / denom) + b1[lane];
    g[(size_t)v * F1 + lane] = t > 0.f ? t : (__expf(t) - 1.f);  // ELU
}

// ---------------- GEMM2 + attention dots layer 2 ----------------

__global__ __launch_bounds__(256) void k_gemm2(const float* __restrict__ g,
                                               const float* __restrict__ W2,
                                               const float* __restrict__ as2w,
                                               const float* __restrict__ ad2w,
                                               float* __restrict__ h2,
                                               float* __restrict__ a_s2,
                                               float* __restrict__ a_d2, int N) {
    __shared__ float W2s[F1][NCLS];
    int tid = threadIdx.x;
    for (int i = tid; i < F1 * NCLS; i += 256) ((float*)W2s)[i] = W2[i];
    __syncthreads();
    int lane = tid & 63, wid = tid >> 6;
    int n = blockIdx.x * 16 + wid * 4 + (lane >> 4);
    int c = lane & 15;
    if (n >= N) return;
    float acc = 0.f;
#pragma unroll
    for (int k4 = 0; k4 < 16; k4++) {
        float4 gv = *(const float4*)(g + (size_t)n * F1 + k4 * 4);
        acc = fmaf(gv.x, W2s[k4 * 4 + 0][c], acc);
        acc = fmaf(gv.y, W2s[k4 * 4 + 1][c], acc);
        acc = fmaf(gv.z, W2s[k4 * 4 + 2][c], acc);
        acc = fmaf(gv.w, W2s[k4 * 4 + 3][c], acc);
    }
    h2[(size_t)n * NCLS + c] = acc;
    float s = acc * as2w[c];
    float d = acc * ad2w[c];
    s += __shfl_xor(s, 1); s += __shfl_xor(s, 2); s += __shfl_xor(s, 4); s += __shfl_xor(s, 8);
    d += __shfl_xor(d, 1); d += __shfl_xor(d, 2); d += __shfl_xor(d, 4); d += __shfl_xor(d, 8);
    if (c == 0) { a_s2[n] = s; a_d2[n] = d; }
}

// ---------------- layer-2 aggregation (single-pass) -> fp32 output ----------

__global__ __launch_bounds__(256) void k_agg2(const float* __restrict__ h2,
                                              const float* __restrict__ a_s2,
                                              const float* __restrict__ a_d2,
                                              const float* __restrict__ b2,
                                              const unsigned* __restrict__ row_ptr,
                                              const unsigned* __restrict__ ssrc,
                                              float* __restrict__ out, int N) {
    int wid = threadIdx.x >> 6, lane = threadIdx.x & 63;
    int v = blockIdx.x * 4 + wid;
    if (v >= N) return;
    unsigned base = row_ptr[v];
    unsigned deg = row_ptr[v + 1] - base;
    float adv = a_d2[v];
    int sub = lane >> 4, c = lane & 15;

    float denom = 0.f, acc = 0.f;
    unsigned j = sub;
    for (; j + 12 < deg; j += 16) {
        unsigned s0 = ssrc[base + j + 0];
        unsigned s1 = ssrc[base + j + 4];
        unsigned s2 = ssrc[base + j + 8];
        unsigned s3 = ssrc[base + j + 12];
        float as0 = a_s2[s0];
        float as1 = a_s2[s1];
        float as2 = a_s2[s2];
        float as3 = a_s2[s3];
        float h0 = h2[(size_t)s0 * NCLS + c];
        float h1v = h2[(size_t)s1 * NCLS + c];
        float h2v = h2[(size_t)s2 * NCLS + c];
        float h3 = h2[(size_t)s3 * NCLS + c];
        float e0 = as0 + adv; e0 = e0 > 0.f ? e0 : NEG_SLOPE * e0; float p0 = __expf(e0);
        float e1 = as1 + adv; e1 = e1 > 0.f ? e1 : NEG_SLOPE * e1; float p1 = __expf(e1);
        float e2 = as2 + adv; e2 = e2 > 0.f ? e2 : NEG_SLOPE * e2; float p2 = __expf(e2);
        float e3 = as3 + adv; e3 = e3 > 0.f ? e3 : NEG_SLOPE * e3; float p3 = __expf(e3);
        denom += (p0 + p1) + (p2 + p3);
        acc = fmaf(h0, p0, acc);
        acc = fmaf(h1v, p1, acc);
        acc = fmaf(h2v, p2, acc);
        acc = fmaf(h3, p3, acc);
    }
    for (; j < deg; j += 4) {
        unsigned s = ssrc[base + j];
        float as = a_s2[s];
        float hv = h2[(size_t)s * NCLS + c];
        float e = as + adv; e = e > 0.f ? e : NEG_SLOPE * e;
        float p = __expf(e);
        denom += p;
        acc = fmaf(hv, p, acc);
    }
    acc += __shfl_xor(acc, 16);
    acc += __shfl_xor(acc, 32);
    denom += __shfl_xor(denom, 16);
    denom += __shfl_xor(denom, 32);
    if (lane < 16) {
        out[(size_t)v * NCLS + c] = acc * (1.0f / denom) + b2[c];
    }
}

// ---------------- launch ----------------

static inline size_t algn(size_t x) { return (x + 255) & ~(size_t)255; }

extern "C" void kernel_launch(void* const* d_in, const int* in_sizes, int n_in,
                              void* d_out, int out_size, void* d_ws, size_t ws_size,
                              hipStream_t stream) {
    const float* x   = (const float*)d_in[0];
    const int* ei    = (const int*)d_in[1];
    const float* W1  = (const float*)d_in[2];
    const float* as1 = (const float*)d_in[3];
    const float* ad1 = (const float*)d_in[4];
    const float* b1  = (const float*)d_in[5];
    const float* W2  = (const float*)d_in[6];
    const float* as2 = (const float*)d_in[7];
    const float* ad2 = (const float*)d_in[8];
    const float* b2  = (const float*)d_in[9];

    const int N = in_sizes[0] / F_IN;
    const int E = in_sizes[1] / 2;
    const int ET = E + N;

    // coarse buckets for the CSR sort (nodes-per-bucket = 1<<shift, nb <= 1024)
    int shift = 8;
    int nb = (N + 255) >> 8;
    while (nb > 1024) { shift++; nb = (N + (1 << shift) - 1) >> shift; }

    const int GA_T = ((N / 2) + 63) / 64;       // gemm tiles in half A
    const int rowSplit = GA_T * 64;
    const int GB_T = (N - rowSplit + 63) / 64;  // gemm tiles in half B

    char* p = (char*)d_ws;
    unsigned short* h1b = (unsigned short*)p;  p += algn((size_t)N * F1 * 2);
    float* g    = (float*)p;      p += algn((size_t)N * F1 * 4);
    float* a_s1 = (float*)p;      p += algn((size_t)N * 8 * 4);
    float* a_d1 = (float*)p;      p += algn((size_t)N * 8 * 4);
    float* h2   = (float*)p;      p += algn((size_t)N * NCLS * 4);
    float* a_s2 = (float*)p;      p += algn((size_t)N * 4);
    float* a_d2 = (float*)p;      p += algn((size_t)N * 4);
    unsigned* row_ptr = (unsigned*)p;  p += algn((size_t)(N + 1) * 4);
    unsigned* bucketCnt  = (unsigned*)p;  p += algn((size_t)1024 * 4);
    unsigned* bucketOfs  = (unsigned*)p;  p += algn((size_t)1024 * 4);
    unsigned* bucketFill = (unsigned*)p;  p += algn((size_t)1024 * 4);
    unsigned* mode    = (unsigned*)p;  p += algn(256);
    unsigned* ssrc = (unsigned*)p;     p += algn((size_t)ET * 4);
    // pairs[] lifetime (fusedB -> k_sort) is disjoint from g[] (agg1 -> gemm2):
    // alias to save workspace. ET*4 (13.2 MB) <= N*F1*4 (25.6 MB).
    unsigned* pairs = (unsigned*)g;

    hipMemsetAsync(bucketCnt, 0, (size_t)nb * 4, stream);

    dim3 b256(256);
    k_detect<<<dim3(1), dim3(64), 0, stream>>>(ei, E, mode);

    // A: gemm rows [0,rowSplit) interleaved with edge decode + bucket hist
    k_fusedA<<<dim3(2 * GA_T), b256, 0, stream>>>(x, W1, as1, ad1, h1b, a_s1, a_d1, N,
                                                  ei, mode, bucketCnt,
                                                  E, ET, GA_T, nb, shift);

    k_scan_buckets<<<dim3(1), dim3(1024), 0, stream>>>(bucketCnt, nb, ET, bucketOfs,
                                                       bucketFill, row_ptr, N);

    // B: gemm rows [rowSplit,N) interleaved with bucket scatter
    k_fusedB<<<dim3(2 * GB_T), b256, 0, stream>>>(x, W1, as1, ad1, h1b, a_s1, a_d1, N,
                                                  rowSplit, ei, mode, bucketFill,
                                                  pairs, E, ET, GB_T, nb, shift);

    // bucket -> per-node CSR (builds row_ptr + ssrc)
    k_sort<<<dim3(nb), b256, 0, stream>>>(pairs, bucketOfs, bucketCnt, row_ptr, ssrc, N, shift);

    k_agg1<<<dim3((N + 3) / 4), b256, 0, stream>>>(h1b, a_s1, a_d1, b1, row_ptr, ssrc, g, N);
    k_gemm2<<<dim3((N + 15) / 16), b256, 0, stream>>>(g, W2, as2, ad2, h2, a_s2, a_d2, N);
    k_agg2<<<dim3((N + 3) / 4), b256, 0, stream>>>(h2, a_s2, a_d2, b2, row_ptr, ssrc,
                                                   (float*)d_out, N);
}

// Round 4
// 631.676 us; speedup vs baseline: 1.2212x; 1.0135x over previous
//
#include <hip/hip_runtime.h>

// Problem constants (from reference setup_inputs)
#define F_IN 512
#define F1 64          // HEADS*HID = 8*8
#define NCLS 16
#define NEG_SLOPE 0.2f

typedef __attribute__((ext_vector_type(8))) short short8;
typedef __attribute__((ext_vector_type(4))) float f32x4;

__device__ __forceinline__ unsigned short f2bf(float f) {
    unsigned u = __float_as_uint(f);
    return (unsigned short)((u + 0x7fffu + ((u >> 16) & 1u)) >> 16);
}
__device__ __forceinline__ float bf2f(unsigned short u) {
    return __uint_as_float(((unsigned)u) << 16);
}

// ---------------- edge decode (int32 vs int64 robust) ----------------

__global__ __launch_bounds__(64) void k_detect(const int* __restrict__ ei, int E,
                                               unsigned* __restrict__ mode) {
    int t = threadIdx.x;
    unsigned nz = 0;
    int lim = (E > 256) ? 256 : E;
    for (int k = t; k < lim; k += 64) nz |= (unsigned)ei[2 * k + 1];
    for (int off = 1; off < 64; off <<= 1) nz |= __shfl_xor(nz, off);
    if (t == 0) *mode = (nz == 0) ? 1u : 0u;   // 1 = int64 layout
}

__device__ __forceinline__ void decode_edge(const int* __restrict__ ei,
                                            const long long* __restrict__ e64,
                                            bool m64, unsigned i, int E, int N,
                                            int& s, int& v) {
    if (i < (unsigned)E) {
        if (m64) { s = (int)e64[i]; v = (int)e64[E + i]; }
        else     { s = ei[i];       v = ei[E + i]; }
    } else {
        s = (int)(i - (unsigned)E);
        v = s;
    }
    s = s < 0 ? 0 : (s >= N ? N - 1 : s);
    v = v < 0 ? 0 : (v >= N ? N - 1 : v);
}

__device__ __forceinline__ int decode_dst(const int* __restrict__ ei,
                                          const long long* __restrict__ e64,
                                          bool m64, unsigned i, int E, int N) {
    int v;
    if (i < (unsigned)E) v = m64 ? (int)e64[E + i] : ei[E + i];
    else                 v = (int)(i - (unsigned)E);
    return v < 0 ? 0 : (v >= N ? N - 1 : v);
}

// ---------------- W1 pre-convert: fp32 [512][64] -> bf16 transposed [64][512]

__global__ __launch_bounds__(256) void k_prep(const float* __restrict__ W1,
                                              unsigned short* __restrict__ W1T) {
    int t = blockIdx.x * 256 + threadIdx.x;
    if (t < F_IN * F1) {
        int k = t >> 6, c = t & 63;
        W1T[(size_t)c * F_IN + k] = f2bf(W1[t]);
    }
}

// ---------------- GEMM1 MFMA tile (bf16 in, fp32 acc) ----------------
// 64 rows x 64 cols per block, K=512 in chunks of 32. 4 waves; wave w owns
// rows w*16..w*16+15 as 4 MFMA 16x16 col-tiles. Fragment layouts (verified
// per guide §3): A[m=lane&15][k=quad*8+j]; B[k=quad*8+j][n=lane&15];
// C/D col=lane&15, row=quad*4+reg. B comes pre-converted/transposed (W1T).

__device__ __forceinline__ void gemm1_tile(const float* __restrict__ x,
                                           const unsigned short* __restrict__ W1T,
                                           const float* __restrict__ att_s,
                                           const float* __restrict__ att_d,
                                           unsigned short* __restrict__ h1b,
                                           float* __restrict__ a_s1,
                                           float* __restrict__ a_d1,
                                           int N, int row0,
                                           unsigned short (*Abuf)[40],
                                           unsigned short (*BbufT)[40]) {
    const int tid = threadIdx.x;
    const int w = tid >> 6, lane = tid & 63;
    const int quad = lane >> 4, r16 = lane & 15;

    f32x4 acc[4];
#pragma unroll
    for (int t = 0; t < 4; t++) acc[t] = (f32x4){0.f, 0.f, 0.f, 0.f};

    const int a_row = tid >> 2;             // 0..63
    const int a_seg = (tid & 3) * 8;        // 0,8,16,24
    const int b_col = tid & 63;             // 0..63
    const int b_kq  = tid >> 6;             // 0..3 (wave id)
    const int ar = row0 + a_row;

    for (int k0 = 0; k0 < F_IN; k0 += 32) {
        {
            float4 v0 = make_float4(0.f, 0.f, 0.f, 0.f), v1 = v0;
            if (ar < N) {
                const float* xp = x + (size_t)ar * F_IN + k0 + a_seg;
                v0 = *(const float4*)xp;
                v1 = *(const float4*)(xp + 4);
            }
            short8 cv;
            cv[0] = (short)f2bf(v0.x); cv[1] = (short)f2bf(v0.y);
            cv[2] = (short)f2bf(v0.z); cv[3] = (short)f2bf(v0.w);
            cv[4] = (short)f2bf(v1.x); cv[5] = (short)f2bf(v1.y);
            cv[6] = (short)f2bf(v1.z); cv[7] = (short)f2bf(v1.w);
            *(short8*)&Abuf[a_row][a_seg] = cv;
        }
        {
            const unsigned short* wp = W1T + (size_t)b_col * F_IN + k0 + b_kq * 8;
            *(short8*)&BbufT[b_col][b_kq * 8] = *(const short8*)wp;
        }
        __syncthreads();

        short8 af = *(const short8*)&Abuf[w * 16 + r16][quad * 8];
#pragma unroll
        for (int t = 0; t < 4; t++) {
            short8 bf = *(const short8*)&BbufT[t * 16 + r16][quad * 8];
            acc[t] = __builtin_amdgcn_mfma_f32_16x16x32_bf16(af, bf, acc[t], 0, 0, 0);
        }
        __syncthreads();
    }

    // epilogue
    float ats[4], atd[4];
#pragma unroll
    for (int t = 0; t < 4; t++) {
        ats[t] = att_s[t * 16 + r16];
        atd[t] = att_d[t * 16 + r16];
    }
#pragma unroll
    for (int r = 0; r < 4; r++) {
        int grow = row0 + w * 16 + quad * 4 + r;
        bool ok = grow < N;
        float ps[4], pd[4];
#pragma unroll
        for (int t = 0; t < 4; t++) {
            float vv = acc[t][r];
            if (ok) h1b[(size_t)grow * F1 + t * 16 + r16] = f2bf(vv);
            ps[t] = vv * ats[t];
            pd[t] = vv * atd[t];
        }
#pragma unroll
        for (int t = 0; t < 4; t++) {
            ps[t] += __shfl_xor(ps[t], 1); pd[t] += __shfl_xor(pd[t], 1);
            ps[t] += __shfl_xor(ps[t], 2); pd[t] += __shfl_xor(pd[t], 2);
            ps[t] += __shfl_xor(ps[t], 4); pd[t] += __shfl_xor(pd[t], 4);
        }
        if (ok && (r16 & 7) == 0) {
            int hh0 = r16 >> 3;   // 0 or 1
#pragma unroll
            for (int t = 0; t < 4; t++) {
                a_s1[(size_t)grow * 8 + t * 2 + hh0] = ps[t];
                a_d1[(size_t)grow * 8 + t * 2 + hh0] = pd[t];
            }
        }
    }
}

// ---------------- fused A: gemm1 (rows [0,rowSplit)) || bucket histogram ----

__global__ __launch_bounds__(256) void k_fusedA(const float* __restrict__ x,
                                                const unsigned short* __restrict__ W1T,
                                                const float* __restrict__ att_s,
                                                const float* __restrict__ att_d,
                                                unsigned short* __restrict__ h1b,
                                                float* __restrict__ a_s1,
                                                float* __restrict__ a_d1, int N,
                                                const int* __restrict__ ei,
                                                const unsigned* __restrict__ mode,
                                                unsigned* __restrict__ bucketCnt,
                                                int E, int ET, int nch,
                                                int nb, int shift) {
    __shared__ __align__(16) char smem[10240];
    unsigned b = blockIdx.x;
    if ((b & 1) == 0) {
        gemm1_tile(x, W1T, att_s, att_d, h1b, a_s1, a_d1, N, (int)(b >> 1) * 64,
                   (unsigned short (*)[40])smem,
                   (unsigned short (*)[40])(smem + 5120));
        return;
    }
    unsigned* cntL = (unsigned*)smem;  // [1024]
    for (int i = threadIdx.x; i < 1024; i += 256) cntL[i] = 0u;
    __syncthreads();

    const unsigned stride = (unsigned)nch * 256u;
    bool m64 = (*mode != 0u);
    const long long* e64 = (const long long*)ei;
    unsigned i = (b >> 1) * 256u + threadIdx.x;
    for (; i + 3u * stride < (unsigned)ET; i += 4u * stride) {
        int v0 = decode_dst(ei, e64, m64, i, E, N);
        int v1 = decode_dst(ei, e64, m64, i + stride, E, N);
        int v2 = decode_dst(ei, e64, m64, i + 2u * stride, E, N);
        int v3 = decode_dst(ei, e64, m64, i + 3u * stride, E, N);
        atomicAdd(&cntL[(unsigned)v0 >> shift], 1u);
        atomicAdd(&cntL[(unsigned)v1 >> shift], 1u);
        atomicAdd(&cntL[(unsigned)v2 >> shift], 1u);
        atomicAdd(&cntL[(unsigned)v3 >> shift], 1u);
    }
    for (; i < (unsigned)ET; i += stride) {
        int v = decode_dst(ei, e64, m64, i, E, N);
        atomicAdd(&cntL[(unsigned)v >> shift], 1u);
    }
    __syncthreads();
    for (int k = threadIdx.x; k < nb; k += 256) {
        unsigned c = cntL[k];
        if (c) atomicAdd(&bucketCnt[k], c);
    }
}

// ---------------- fused B: gemm1 (rows [rowSplit,N)) || bucket scatter ------

__global__ __launch_bounds__(256) void k_fusedB(const float* __restrict__ x,
                                                const unsigned short* __restrict__ W1T,
                                                const float* __restrict__ att_s,
                                                const float* __restrict__ att_d,
                                                unsigned short* __restrict__ h1b,
                                                float* __restrict__ a_s1,
                                                float* __restrict__ a_d1, int N,
                                                int rowSplit,
                                                const int* __restrict__ ei,
                                                const unsigned* __restrict__ mode,
                                                unsigned* __restrict__ bucketFill,
                                                unsigned* __restrict__ pairs,
                                                int E, int ET, int nch,
                                                int nb, int shift) {
    __shared__ __align__(16) char smem[10240];
    unsigned b = blockIdx.x;
    if (b & 1) {
        gemm1_tile(x, W1T, att_s, att_d, h1b, a_s1, a_d1, N,
                   rowSplit + (int)(b >> 1) * 64,
                   (unsigned short (*)[40])smem,
                   (unsigned short (*)[40])(smem + 5120));
        return;
    }
    unsigned* cntA = (unsigned*)smem;           // [1024] counts -> span delta
    unsigned* ofsA = (unsigned*)(smem + 4096);  // [1024] local excl ofs -> cursor
    unsigned* part = (unsigned*)(smem + 8192);  // [256]
    const int t = threadIdx.x;
    const int chunk = (ET + nch - 1) / nch;
    const int cbase = (int)(b >> 1) * chunk;
    const int cend = (cbase + chunk < ET) ? cbase + chunk : ET;
    const unsigned lmask = (1u << shift) - 1u;
    bool m64 = (*mode != 0u);
    const long long* e64 = (const long long*)ei;

    for (int k = t; k < 1024; k += 256) cntA[k] = 0u;
    __syncthreads();
    // phase 1: count (decode dst only)
    for (int k = cbase + t; k < cend; k += 256) {
        int v = decode_dst(ei, e64, m64, (unsigned)k, E, N);
        atomicAdd(&cntA[(unsigned)v >> shift], 1u);
    }
    __syncthreads();
    // exclusive scan over 1024 entries (4 per thread)
    unsigned a0 = cntA[4 * t + 0], a1 = cntA[4 * t + 1];
    unsigned a2 = cntA[4 * t + 2], a3 = cntA[4 * t + 3];
    unsigned ssum = a0 + a1 + a2 + a3;
    part[t] = ssum;
    __syncthreads();
    for (int off = 1; off < 256; off <<= 1) {
        unsigned add = (t >= off) ? part[t - off] : 0u;
        __syncthreads();
        part[t] += add;
        __syncthreads();
    }
    unsigned excl = part[t] - ssum;
    ofsA[4 * t + 0] = excl;
    ofsA[4 * t + 1] = excl + a0;
    ofsA[4 * t + 2] = excl + a0 + a1;
    ofsA[4 * t + 3] = excl + a0 + a1 + a2;
    __syncthreads();
    // reserve private global spans; cntA becomes delta = globalBase - localOfs
    for (int k = t; k < nb; k += 256) {
        unsigned c = cntA[k];
        unsigned g = c ? atomicAdd(&bucketFill[k], c) : 0u;
        cntA[k] = g - ofsA[k];
    }
    __syncthreads();
    // phase 2: re-decode and scatter packed records into private spans
    for (int k = cbase + t; k < cend; k += 256) {
        int s, v;
        decode_edge(ei, e64, m64, (unsigned)k, E, N, s, v);
        unsigned bb = (unsigned)v >> shift;
        unsigned slot = atomicAdd(&ofsA[bb], 1u);
        pairs[cntA[bb] + slot] = (unsigned)s | (((unsigned)v & lmask) << 20);
    }
}

// ---------------- bucket scan (global CSR offsets at bucket granularity) ----

__global__ __launch_bounds__(1024) void k_scan_buckets(const unsigned* __restrict__ bucketCnt,
                                                       int nb, int ET,
                                                       unsigned* __restrict__ bucketOfs,
                                                       unsigned* __restrict__ bucketFill,
                                                       unsigned* __restrict__ row_ptr,
                                                       int N) {
    __shared__ unsigned sbuf[1024];
    int t = threadIdx.x;
    unsigned val = (t < nb) ? bucketCnt[t] : 0u;
    sbuf[t] = val;
    __syncthreads();
    for (int off = 1; off < 1024; off <<= 1) {
        unsigned add = (t >= off) ? sbuf[t - off] : 0u;
        __syncthreads();
        sbuf[t] += add;
        __syncthreads();
    }
    if (t < nb) {
        unsigned e = sbuf[t] - val;  // exclusive
        bucketOfs[t] = e;
        bucketFill[t] = e;
    }
    if (t == 0) row_ptr[N] = (unsigned)ET;
}

// ---------------- bucket -> per-node CSR scatter (+ row_ptr build) ----------

__global__ __launch_bounds__(256) void k_sort(const unsigned* __restrict__ pairs,
                                              const unsigned* __restrict__ bucketOfs,
                                              const unsigned* __restrict__ bucketCnt,
                                              unsigned* __restrict__ row_ptr,
                                              unsigned* __restrict__ ssrc,
                                              int N, int shift) {
    __shared__ unsigned f[1024];      // counts -> cursors
    __shared__ unsigned part[256];
    const int b = blockIdx.x;
    const int t = threadIdx.x;
    const int nodes = 1 << shift;     // <= 1024
    const int bbase = b << shift;
    for (int i = t; i < 1024; i += 256) f[i] = 0u;
    __syncthreads();
    const unsigned base = bucketOfs[b];
    const unsigned cnt = bucketCnt[b];
    // pass 1: per-node degree count
    for (unsigned i = (unsigned)t; i < cnt; i += 256u)
        atomicAdd(&f[pairs[base + i] >> 20], 1u);
    __syncthreads();
    // block exclusive scan over 1024 entries (4 per thread)
    unsigned a0 = f[4 * t + 0], a1 = f[4 * t + 1];
    unsigned a2 = f[4 * t + 2], a3 = f[4 * t + 3];
    unsigned ssum = a0 + a1 + a2 + a3;
    part[t] = ssum;
    __syncthreads();
    for (int off = 1; off < 256; off <<= 1) {
        unsigned add = (t >= off) ? part[t - off] : 0u;
        __syncthreads();
        part[t] += add;
        __syncthreads();
    }
    unsigned excl = part[t] - ssum;
    unsigned c0 = base + excl;
    unsigned c1 = c0 + a0;
    unsigned c2 = c1 + a1;
    unsigned c3 = c2 + a2;
    {
        int v0 = bbase + 4 * t;
        if (v0 + 0 < N && 4 * t + 0 < nodes) row_ptr[v0 + 0] = c0;
        if (v0 + 1 < N && 4 * t + 1 < nodes) row_ptr[v0 + 1] = c1;
        if (v0 + 2 < N && 4 * t + 2 < nodes) row_ptr[v0 + 2] = c2;
        if (v0 + 3 < N && 4 * t + 3 < nodes) row_ptr[v0 + 3] = c3;
    }
    f[4 * t + 0] = c0;
    f[4 * t + 1] = c1;
    f[4 * t + 2] = c2;
    f[4 * t + 3] = c3;
    __syncthreads();
    // pass 2: scatter
    for (unsigned i = (unsigned)t; i < cnt; i += 256u) {
        unsigned pk = pairs[base + i];
        unsigned local = pk >> 20;
        unsigned pos = atomicAdd(&f[local], 1u);
        ssrc[pos] = pk & 0xFFFFFu;
    }
}

// ---------------- layer-1 aggregation: one wave per dst node ----------------
// Two-phase batched: phase A computes attention p for 8 edges with lane=(e,h)
// (one exp per (edge,head) -- no 8x redundancy); phase B accumulates 2 edges
// per iter, each half-wave covering 64 channels as 32-bit channel pairs.
// p/s move between phases via shfl (LDS pipe, off the VALU). Tail via p=0.

__global__ __launch_bounds__(256) void k_agg1(const unsigned short* __restrict__ h1b,
                                              const float* __restrict__ a_s1,
                                              const float* __restrict__ a_d1,
                                              const float* __restrict__ b1,
                                              const unsigned* __restrict__ row_ptr,
                                              const unsigned* __restrict__ ssrc,
                                              float* __restrict__ g, int N) {
    int wid = threadIdx.x >> 6, lane = threadIdx.x & 63;
    int v = blockIdx.x * 4 + wid;
    if (v >= N) return;
    unsigned base = row_ptr[v];
    unsigned deg = row_ptr[v + 1] - base;

    const int eA = lane >> 3, hA = lane & 7;      // phase-A mapping
    float adv = a_d1[(size_t)v * 8 + hA];
    const int half = lane >> 5, j32 = lane & 31;  // phase-B mapping
    const int hq = j32 >> 2;                      // head of channel pair

    float denom = 0.f, acc0 = 0.f, acc1 = 0.f;
    for (unsigned jj = 0; jj < deg; jj += 8) {
        // ---- phase A: attention for 8 edges (one (e,h) per lane) ----
        unsigned ee = jj + (unsigned)eA;
        bool val = ee < deg;
        unsigned sL = ssrc[base + (val ? ee : 0u)];
        float as = a_s1[(size_t)sL * 8 + hA];
        float eatt = as + adv;
        eatt = eatt > 0.f ? eatt : NEG_SLOPE * eatt;
        float p = val ? __expf(eatt) : 0.f;
        denom += p;
        // ---- phase B: accumulate 8 edges, 2 per iter (one per half-wave) ----
#pragma unroll
        for (int k = 0; k < 4; k++) {
            int esel = k * 2 + half;
            unsigned s_my = (unsigned)__shfl((int)sL, esel * 8);
            float p_my = __shfl(p, esel * 8 + hq);
            unsigned u = *(const unsigned*)(h1b + ((size_t)s_my << 6) + (j32 << 1));
            float lo = __uint_as_float(u << 16);
            float hi = __uint_as_float(u & 0xffff0000u);
            acc0 = fmaf(lo, p_my, acc0);
            acc1 = fmaf(hi, p_my, acc1);
        }
    }
    // cross-half edge-subset reduce
    acc0 += __shfl_xor(acc0, 32);
    acc1 += __shfl_xor(acc1, 32);
    // denom: sum over e (lanes at stride 8)
    denom += __shfl_xor(denom, 8);
    denom += __shfl_xor(denom, 16);
    denom += __shfl_xor(denom, 32);
    float dn = __shfl(denom, hq);   // denom for my channel pair's head
    if (half == 0) {
        float inv = 1.0f / dn;
        int c0 = j32 * 2;
        float t0 = acc0 * inv + b1[c0];
        float t1 = acc1 * inv + b1[c0 + 1];
        t0 = t0 > 0.f ? t0 : (__expf(t0) - 1.f);
        t1 = t1 > 0.f ? t1 : (__expf(t1) - 1.f);
        *(float2*)&g[(size_t)v * F1 + c0] = make_float2(t0, t1);
    }
}

// ---------------- GEMM2 + attention dots layer 2 ----------------

__global__ __launch_bounds__(256) void k_gemm2(const float* __restrict__ g,
                                               const float* __restrict__ W2,
                                               const float* __restrict__ as2w,
                                               const float* __restrict__ ad2w,
                                               float* __restrict__ h2,
                                               float* __restrict__ a_s2,
                                               float* __restrict__ a_d2, int N) {
    __shared__ float W2s[F1][NCLS];
    int tid = threadIdx.x;
    for (int i = tid; i < F1 * NCLS; i += 256) ((float*)W2s)[i] = W2[i];
    __syncthreads();
    int lane = tid & 63, wid = tid >> 6;
    int n = blockIdx.x * 16 + wid * 4 + (lane >> 4);
    int c = lane & 15;
    if (n >= N) return;
    float acc = 0.f;
#pragma unroll
    for (int k4 = 0; k4 < 16; k4++) {
        float4 gv = *(const float4*)(g + (size_t)n * F1 + k4 * 4);
        acc = fmaf(gv.x, W2s[k4 * 4 + 0][c], acc);
        acc = fmaf(gv.y, W2s[k4 * 4 + 1][c], acc);
        acc = fmaf(gv.z, W2s[k4 * 4 + 2][c], acc);
        acc = fmaf(gv.w, W2s[k4 * 4 + 3][c], acc);
    }
    h2[(size_t)n * NCLS + c] = acc;
    float s = acc * as2w[c];
    float d = acc * ad2w[c];
    s += __shfl_xor(s, 1); s += __shfl_xor(s, 2); s += __shfl_xor(s, 4); s += __shfl_xor(s, 8);
    d += __shfl_xor(d, 1); d += __shfl_xor(d, 2); d += __shfl_xor(d, 4); d += __shfl_xor(d, 8);
    if (c == 0) { a_s2[n] = s; a_d2[n] = d; }
}

// ---------------- layer-2 aggregation (single-pass) -> fp32 output ----------

__global__ __launch_bounds__(256) void k_agg2(const float* __restrict__ h2,
                                              const float* __restrict__ a_s2,
                                              const float* __restrict__ a_d2,
                                              const float* __restrict__ b2,
                                              const unsigned* __restrict__ row_ptr,
                                              const unsigned* __restrict__ ssrc,
                                              float* __restrict__ out, int N) {
    int wid = threadIdx.x >> 6, lane = threadIdx.x & 63;
    int v = blockIdx.x * 4 + wid;
    if (v >= N) return;
    unsigned base = row_ptr[v];
    unsigned deg = row_ptr[v + 1] - base;
    float adv = a_d2[v];
    int sub = lane >> 4, c = lane & 15;

    float denom = 0.f, acc = 0.f;
    unsigned j = sub;
    for (; j + 12 < deg; j += 16) {
        unsigned s0 = ssrc[base + j + 0];
        unsigned s1 = ssrc[base + j + 4];
        unsigned s2 = ssrc[base + j + 8];
        unsigned s3 = ssrc[base + j + 12];
        float as0 = a_s2[s0];
        float as1 = a_s2[s1];
        float as2 = a_s2[s2];
        float as3 = a_s2[s3];
        float h0 = h2[(size_t)s0 * NCLS + c];
        float h1v = h2[(size_t)s1 * NCLS + c];
        float h2v = h2[(size_t)s2 * NCLS + c];
        float h3 = h2[(size_t)s3 * NCLS + c];
        float e0 = as0 + adv; e0 = e0 > 0.f ? e0 : NEG_SLOPE * e0; float p0 = __expf(e0);
        float e1 = as1 + adv; e1 = e1 > 0.f ? e1 : NEG_SLOPE * e1; float p1 = __expf(e1);
        float e2 = as2 + adv; e2 = e2 > 0.f ? e2 : NEG_SLOPE * e2; float p2 = __expf(e2);
        float e3 = as3 + adv; e3 = e3 > 0.f ? e3 : NEG_SLOPE * e3; float p3 = __expf(e3);
        denom += (p0 + p1) + (p2 + p3);
        acc = fmaf(h0, p0, acc);
        acc = fmaf(h1v, p1, acc);
        acc = fmaf(h2v, p2, acc);
        acc = fmaf(h3, p3, acc);
    }
    for (; j < deg; j += 4) {
        unsigned s = ssrc[base + j];
        float as = a_s2[s];
        float hv = h2[(size_t)s * NCLS + c];
        float e = as + adv; e = e > 0.f ? e : NEG_SLOPE * e;
        float p = __expf(e);
        denom += p;
        acc = fmaf(hv, p, acc);
    }
    acc += __shfl_xor(acc, 16);
    acc += __shfl_xor(acc, 32);
    denom += __shfl_xor(denom, 16);
    denom += __shfl_xor(denom, 32);
    if (lane < 16) {
        out[(size_t)v * NCLS + c] = acc * (1.0f / denom) + b2[c];
    }
}

// ---------------- launch ----------------

static inline size_t algn(size_t x) { return (x + 255) & ~(size_t)255; }

extern "C" void kernel_launch(void* const* d_in, const int* in_sizes, int n_in,
                              void* d_out, int out_size, void* d_ws, size_t ws_size,
                              hipStream_t stream) {
    const float* x   = (const float*)d_in[0];
    const int* ei    = (const int*)d_in[1];
    const float* W1  = (const float*)d_in[2];
    const float* as1 = (const float*)d_in[3];
    const float* ad1 = (const float*)d_in[4];
    const float* b1  = (const float*)d_in[5];
    const float* W2  = (const float*)d_in[6];
    const float* as2 = (const float*)d_in[7];
    const float* ad2 = (const float*)d_in[8];
    const float* b2  = (const float*)d_in[9];

    const int N = in_sizes[0] / F_IN;
    const int E = in_sizes[1] / 2;
    const int ET = E + N;

    // coarse buckets for the CSR sort (nodes-per-bucket = 1<<shift, nb <= 1024)
    int shift = 8;
    int nb = (N + 255) >> 8;
    while (nb > 1024) { shift++; nb = (N + (1 << shift) - 1) >> shift; }

    const int GA_T = ((N / 2) + 63) / 64;       // gemm tiles in half A
    const int rowSplit = GA_T * 64;
    const int GB_T = (N - rowSplit + 63) / 64;  // gemm tiles in half B

    char* p = (char*)d_ws;
    unsigned short* h1b = (unsigned short*)p;  p += algn((size_t)N * F1 * 2);
    float* g    = (float*)p;      p += algn((size_t)N * F1 * 4);
    float* a_s1 = (float*)p;      p += algn((size_t)N * 8 * 4);
    float* a_d1 = (float*)p;      p += algn((size_t)N * 8 * 4);
    float* h2   = (float*)p;      p += algn((size_t)N * NCLS * 4);
    float* a_s2 = (float*)p;      p += algn((size_t)N * 4);
    float* a_d2 = (float*)p;      p += algn((size_t)N * 4);
    unsigned* row_ptr = (unsigned*)p;  p += algn((size_t)(N + 1) * 4);
    unsigned* bucketCnt  = (unsigned*)p;  p += algn((size_t)1024 * 4);
    unsigned* bucketOfs  = (unsigned*)p;  p += algn((size_t)1024 * 4);
    unsigned* bucketFill = (unsigned*)p;  p += algn((size_t)1024 * 4);
    unsigned* mode    = (unsigned*)p;  p += algn(256);
    unsigned short* W1T = (unsigned short*)p;  p += algn((size_t)F_IN * F1 * 2);
    unsigned* ssrc = (unsigned*)p;     p += algn((size_t)ET * 4);
    // pairs[] lifetime (fusedB -> k_sort) is disjoint from g[] (agg1 -> gemm2):
    // alias to save workspace. ET*4 (13.2 MB) <= N*F1*4 (25.6 MB).
    unsigned* pairs = (unsigned*)g;

    hipMemsetAsync(bucketCnt, 0, (size_t)nb * 4, stream);

    dim3 b256(256);
    k_detect<<<dim3(1), dim3(64), 0, stream>>>(ei, E, mode);
    k_prep<<<dim3((F_IN * F1 + 255) / 256), b256, 0, stream>>>(W1, W1T);

    // A: gemm rows [0,rowSplit) interleaved with edge decode + bucket hist
    k_fusedA<<<dim3(2 * GA_T), b256, 0, stream>>>(x, W1T, as1, ad1, h1b, a_s1, a_d1, N,
                                                  ei, mode, bucketCnt,
                                                  E, ET, GA_T, nb, shift);

    k_scan_buckets<<<dim3(1), dim3(1024), 0, stream>>>(bucketCnt, nb, ET, bucketOfs,
                                                       bucketFill, row_ptr, N);

    // B: gemm rows [rowSplit,N) interleaved with bucket scatter
    k_fusedB<<<dim3(2 * GB_T), b256, 0, stream>>>(x, W1T, as1, ad1, h1b, a_s1, a_d1, N,
                                                  rowSplit, ei, mode, bucketFill,
                                                  pairs, E, ET, GB_T, nb, shift);

    // bucket -> per-node CSR (builds row_ptr + ssrc)
    k_sort<<<dim3(nb), b256, 0, stream>>>(pairs, bucketOfs, bucketCnt, row_ptr, ssrc, N, shift);

    k_agg1<<<dim3((N + 3) / 4), b256, 0, stream>>>(h1b, a_s1, a_d1, b1, row_ptr, ssrc, g, N);
    k_gemm2<<<dim3((N + 15) / 16), b256, 0, stream>>>(g, W2, as2, ad2, h2, a_s2, a_d2, N);
    k_agg2<<<dim3((N + 3) / 4), b256, 0, stream>>>(h2, a_s2, a_d2, b2, row_ptr, ssrc,
                                                   (float*)d_out, N);
}

// Round 6
// 596.731 us; speedup vs baseline: 1.2927x; 1.0586x over previous
//
#include <hip/hip_runtime.h>
#include <hip/hip_fp16.h>

// Problem constants (from reference setup_inputs)
#define F_IN 512
#define F1 64          // HEADS*HID = 8*8
#define NCLS 16
#define NEG_SLOPE 0.2f

typedef __attribute__((ext_vector_type(8))) short short8;
typedef __attribute__((ext_vector_type(4))) float f32x4;

__device__ __forceinline__ unsigned short f2bf(float f) {
    unsigned u = __float_as_uint(f);
    return (unsigned short)((u + 0x7fffu + ((u >> 16) & 1u)) >> 16);
}
__device__ __forceinline__ float bf2f(unsigned short u) {
    return __uint_as_float(((unsigned)u) << 16);
}

// ---------------- edge decode (int32 vs int64 robust) ----------------

__global__ __launch_bounds__(64) void k_detect(const int* __restrict__ ei, int E,
                                               unsigned* __restrict__ mode) {
    int t = threadIdx.x;
    unsigned nz = 0;
    int lim = (E > 256) ? 256 : E;
    for (int k = t; k < lim; k += 64) nz |= (unsigned)ei[2 * k + 1];
    for (int off = 1; off < 64; off <<= 1) nz |= __shfl_xor(nz, off);
    if (t == 0) *mode = (nz == 0) ? 1u : 0u;   // 1 = int64 layout
}

__device__ __forceinline__ void decode_edge(const int* __restrict__ ei,
                                            const long long* __restrict__ e64,
                                            bool m64, unsigned i, int E, int N,
                                            int& s, int& v) {
    if (i < (unsigned)E) {
        if (m64) { s = (int)e64[i]; v = (int)e64[E + i]; }
        else     { s = ei[i];       v = ei[E + i]; }
    } else {
        s = (int)(i - (unsigned)E);
        v = s;
    }
    s = s < 0 ? 0 : (s >= N ? N - 1 : s);
    v = v < 0 ? 0 : (v >= N ? N - 1 : v);
}

__device__ __forceinline__ int decode_dst(const int* __restrict__ ei,
                                          const long long* __restrict__ e64,
                                          bool m64, unsigned i, int E, int N) {
    int v;
    if (i < (unsigned)E) v = m64 ? (int)e64[E + i] : ei[E + i];
    else                 v = (int)(i - (unsigned)E);
    return v < 0 ? 0 : (v >= N ? N - 1 : v);
}

// ---------------- W1 pre-convert: fp32 [512][64] -> bf16 transposed [64][512]

__global__ __launch_bounds__(256) void k_prep(const float* __restrict__ W1,
                                              unsigned short* __restrict__ W1T) {
    int t = blockIdx.x * 256 + threadIdx.x;
    if (t < F_IN * F1) {
        int k = t >> 6, c = t & 63;
        W1T[(size_t)c * F_IN + k] = f2bf(W1[t]);
    }
}

// ---------------- GEMM1 MFMA tile (bf16 in, fp32 acc) ----------------
// 64 rows x 64 cols per block, K=512 in chunks of 32. Double-buffered LDS,
// ONE barrier per k-step: issue next-step global loads, MFMA current buffer,
// then ds_write next buffer (compiler inserts vmcnt before the writes).
// Fragment layouts per guide §3. a_s1 written as fp16 (L2-resident for agg1).

__device__ __forceinline__ void gemm1_tile(const float* __restrict__ x,
                                           const unsigned short* __restrict__ W1T,
                                           const float* __restrict__ att_s,
                                           const float* __restrict__ att_d,
                                           unsigned short* __restrict__ h1b,
                                           __half* __restrict__ a_s1,
                                           float* __restrict__ a_d1,
                                           int N, int row0, char* sm) {
    const int tid = threadIdx.x;
    const int w = tid >> 6, lane = tid & 63;
    const int quad = lane >> 4, r16 = lane & 15;

    f32x4 acc[4];
#pragma unroll
    for (int t = 0; t < 4; t++) acc[t] = (f32x4){0.f, 0.f, 0.f, 0.f};

    const int a_row = tid >> 2;             // 0..63
    const int a_seg = (tid & 3) * 8;        // 0,8,16,24
    const int b_col = tid & 63;             // 0..63
    const int b_kq  = tid >> 6;             // 0..3 (wave id)
    const int ar = row0 + a_row;
    const bool arok = ar < N;
    const float* xrow = x + (size_t)ar * F_IN + a_seg;
    const unsigned short* wrow = W1T + (size_t)b_col * F_IN + b_kq * 8;

    // buffers: [buf][64][40] shorts; A at sm+buf*10240, B at +5120
    float4 v0 = make_float4(0.f, 0.f, 0.f, 0.f), v1 = v0;
    short8 rb;
    // prologue: load + store k=0
    if (arok) { v0 = *(const float4*)(xrow); v1 = *(const float4*)(xrow + 4); }
    rb = *(const short8*)(wrow);
    {
        unsigned short (*A)[40] = (unsigned short (*)[40])(sm);
        unsigned short (*B)[40] = (unsigned short (*)[40])(sm + 5120);
        short8 cv;
        cv[0] = (short)f2bf(v0.x); cv[1] = (short)f2bf(v0.y);
        cv[2] = (short)f2bf(v0.z); cv[3] = (short)f2bf(v0.w);
        cv[4] = (short)f2bf(v1.x); cv[5] = (short)f2bf(v1.y);
        cv[6] = (short)f2bf(v1.z); cv[7] = (short)f2bf(v1.w);
        *(short8*)&A[a_row][a_seg] = cv;
        *(short8*)&B[b_col][b_kq * 8] = rb;
    }
    __syncthreads();

    int cur = 0;
#pragma unroll
    for (int k = 0; k < F_IN / 32; k++) {
        // issue next-step loads (latency hides under MFMA below)
        if (k + 1 < F_IN / 32) {
            v0 = make_float4(0.f, 0.f, 0.f, 0.f); v1 = v0;
            if (arok) {
                const float* xp = xrow + (k + 1) * 32;
                v0 = *(const float4*)xp; v1 = *(const float4*)(xp + 4);
            }
            rb = *(const short8*)(wrow + (k + 1) * 32);
        }
        // consume current buffer
        {
            unsigned short (*A)[40] = (unsigned short (*)[40])(sm + cur * 10240);
            unsigned short (*B)[40] = (unsigned short (*)[40])(sm + cur * 10240 + 5120);
            short8 af = *(const short8*)&A[w * 16 + r16][quad * 8];
#pragma unroll
            for (int t = 0; t < 4; t++) {
                short8 bf = *(const short8*)&B[t * 16 + r16][quad * 8];
                acc[t] = __builtin_amdgcn_mfma_f32_16x16x32_bf16(af, bf, acc[t], 0, 0, 0);
            }
        }
        // write next buffer
        if (k + 1 < F_IN / 32) {
            unsigned short (*A)[40] = (unsigned short (*)[40])(sm + (cur ^ 1) * 10240);
            unsigned short (*B)[40] = (unsigned short (*)[40])(sm + (cur ^ 1) * 10240 + 5120);
            short8 cv;
            cv[0] = (short)f2bf(v0.x); cv[1] = (short)f2bf(v0.y);
            cv[2] = (short)f2bf(v0.z); cv[3] = (short)f2bf(v0.w);
            cv[4] = (short)f2bf(v1.x); cv[5] = (short)f2bf(v1.y);
            cv[6] = (short)f2bf(v1.z); cv[7] = (short)f2bf(v1.w);
            *(short8*)&A[a_row][a_seg] = cv;
            *(short8*)&B[b_col][b_kq * 8] = rb;
        }
        __syncthreads();
        cur ^= 1;
    }

    // epilogue
    float ats[4], atd[4];
#pragma unroll
    for (int t = 0; t < 4; t++) {
        ats[t] = att_s[t * 16 + r16];
        atd[t] = att_d[t * 16 + r16];
    }
#pragma unroll
    for (int r = 0; r < 4; r++) {
        int grow = row0 + w * 16 + quad * 4 + r;
        bool ok = grow < N;
        float ps[4], pd[4];
#pragma unroll
        for (int t = 0; t < 4; t++) {
            float vv = acc[t][r];
            if (ok) h1b[(size_t)grow * F1 + t * 16 + r16] = f2bf(vv);
            ps[t] = vv * ats[t];
            pd[t] = vv * atd[t];
        }
#pragma unroll
        for (int t = 0; t < 4; t++) {
            ps[t] += __shfl_xor(ps[t], 1); pd[t] += __shfl_xor(pd[t], 1);
            ps[t] += __shfl_xor(ps[t], 2); pd[t] += __shfl_xor(pd[t], 2);
            ps[t] += __shfl_xor(ps[t], 4); pd[t] += __shfl_xor(pd[t], 4);
        }
        if (ok && (r16 & 7) == 0) {
            int hh0 = r16 >> 3;   // 0 or 1
#pragma unroll
            for (int t = 0; t < 4; t++) {
                a_s1[(size_t)grow * 8 + t * 2 + hh0] = __float2half_rn(ps[t]);
                a_d1[(size_t)grow * 8 + t * 2 + hh0] = pd[t];
            }
        }
    }
}

// ---------------- fused A: gemm1 (rows [0,rowSplit)) || bucket histogram ----

__global__ __launch_bounds__(256) void k_fusedA(const float* __restrict__ x,
                                                const unsigned short* __restrict__ W1T,
                                                const float* __restrict__ att_s,
                                                const float* __restrict__ att_d,
                                                unsigned short* __restrict__ h1b,
                                                __half* __restrict__ a_s1,
                                                float* __restrict__ a_d1, int N,
                                                const int* __restrict__ ei,
                                                const unsigned* __restrict__ mode,
                                                unsigned* __restrict__ bucketCnt,
                                                int E, int ET, int nch,
                                                int nb, int shift) {
    __shared__ __align__(16) char smem[20480];
    unsigned b = blockIdx.x;
    if ((b & 1) == 0) {
        gemm1_tile(x, W1T, att_s, att_d, h1b, a_s1, a_d1, N, (int)(b >> 1) * 64, smem);
        return;
    }
    unsigned* cntL = (unsigned*)smem;  // [1024]
    for (int i = threadIdx.x; i < 1024; i += 256) cntL[i] = 0u;
    __syncthreads();

    const unsigned stride = (unsigned)nch * 256u;
    bool m64 = (*mode != 0u);
    const long long* e64 = (const long long*)ei;
    unsigned i = (b >> 1) * 256u + threadIdx.x;
    for (; i + 3u * stride < (unsigned)ET; i += 4u * stride) {
        int v0 = decode_dst(ei, e64, m64, i, E, N);
        int v1 = decode_dst(ei, e64, m64, i + stride, E, N);
        int v2 = decode_dst(ei, e64, m64, i + 2u * stride, E, N);
        int v3 = decode_dst(ei, e64, m64, i + 3u * stride, E, N);
        atomicAdd(&cntL[(unsigned)v0 >> shift], 1u);
        atomicAdd(&cntL[(unsigned)v1 >> shift], 1u);
        atomicAdd(&cntL[(unsigned)v2 >> shift], 1u);
        atomicAdd(&cntL[(unsigned)v3 >> shift], 1u);
    }
    for (; i < (unsigned)ET; i += stride) {
        int v = decode_dst(ei, e64, m64, i, E, N);
        atomicAdd(&cntL[(unsigned)v >> shift], 1u);
    }
    __syncthreads();
    for (int k = threadIdx.x; k < nb; k += 256) {
        unsigned c = cntL[k];
        if (c) atomicAdd(&bucketCnt[k], c);
    }
}

// ---------------- fused B: gemm1 (rows [rowSplit,N)) || bucket scatter ------

__global__ __launch_bounds__(256) void k_fusedB(const float* __restrict__ x,
                                                const unsigned short* __restrict__ W1T,
                                                const float* __restrict__ att_s,
                                                const float* __restrict__ att_d,
                                                unsigned short* __restrict__ h1b,
                                                __half* __restrict__ a_s1,
                                                float* __restrict__ a_d1, int N,
                                                int rowSplit,
                                                const int* __restrict__ ei,
                                                const unsigned* __restrict__ mode,
                                                unsigned* __restrict__ bucketFill,
                                                unsigned* __restrict__ pairs,
                                                int E, int ET, int nch,
                                                int nb, int shift) {
    __shared__ __align__(16) char smem[20480];
    unsigned b = blockIdx.x;
    if (b & 1) {
        gemm1_tile(x, W1T, att_s, att_d, h1b, a_s1, a_d1, N,
                   rowSplit + (int)(b >> 1) * 64, smem);
        return;
    }
    unsigned* cntA = (unsigned*)smem;           // [1024] counts -> span delta
    unsigned* ofsA = (unsigned*)(smem + 4096);  // [1024] local excl ofs -> cursor
    unsigned* part = (unsigned*)(smem + 8192);  // [256]
    const int t = threadIdx.x;
    const int chunk = (ET + nch - 1) / nch;
    const int cbase = (int)(b >> 1) * chunk;
    const int cend = (cbase + chunk < ET) ? cbase + chunk : ET;
    const unsigned lmask = (1u << shift) - 1u;
    bool m64 = (*mode != 0u);
    const long long* e64 = (const long long*)ei;

    for (int k = t; k < 1024; k += 256) cntA[k] = 0u;
    __syncthreads();
    // phase 1: count (decode dst only)
    for (int k = cbase + t; k < cend; k += 256) {
        int v = decode_dst(ei, e64, m64, (unsigned)k, E, N);
        atomicAdd(&cntA[(unsigned)v >> shift], 1u);
    }
    __syncthreads();
    // exclusive scan over 1024 entries (4 per thread)
    unsigned a0 = cntA[4 * t + 0], a1 = cntA[4 * t + 1];
    unsigned a2 = cntA[4 * t + 2], a3 = cntA[4 * t + 3];
    unsigned ssum = a0 + a1 + a2 + a3;
    part[t] = ssum;
    __syncthreads();
    for (int off = 1; off < 256; off <<= 1) {
        unsigned add = (t >= off) ? part[t - off] : 0u;
        __syncthreads();
        part[t] += add;
        __syncthreads();
    }
    unsigned excl = part[t] - ssum;
    ofsA[4 * t + 0] = excl;
    ofsA[4 * t + 1] = excl + a0;
    ofsA[4 * t + 2] = excl + a0 + a1;
    ofsA[4 * t + 3] = excl + a0 + a1 + a2;
    __syncthreads();
    // reserve private global spans; cntA becomes delta = globalBase - localOfs
    for (int k = t; k < nb; k += 256) {
        unsigned c = cntA[k];
        unsigned g = c ? atomicAdd(&bucketFill[k], c) : 0u;
        cntA[k] = g - ofsA[k];
    }
    __syncthreads();
    // phase 2: re-decode and scatter packed records into private spans
    for (int k = cbase + t; k < cend; k += 256) {
        int s, v;
        decode_edge(ei, e64, m64, (unsigned)k, E, N, s, v);
        unsigned bb = (unsigned)v >> shift;
        unsigned slot = atomicAdd(&ofsA[bb], 1u);
        pairs[cntA[bb] + slot] = (unsigned)s | (((unsigned)v & lmask) << 20);
    }
}

// ---------------- bucket scan (global CSR offsets at bucket granularity) ----

__global__ __launch_bounds__(1024) void k_scan_buckets(const unsigned* __restrict__ bucketCnt,
                                                       int nb, int ET,
                                                       unsigned* __restrict__ bucketOfs,
                                                       unsigned* __restrict__ bucketFill,
                                                       unsigned* __restrict__ row_ptr,
                                                       int N) {
    __shared__ unsigned sbuf[1024];
    int t = threadIdx.x;
    unsigned val = (t < nb) ? bucketCnt[t] : 0u;
    sbuf[t] = val;
    __syncthreads();
    for (int off = 1; off < 1024; off <<= 1) {
        unsigned add = (t >= off) ? sbuf[t - off] : 0u;
        __syncthreads();
        sbuf[t] += add;
        __syncthreads();
    }
    if (t < nb) {
        unsigned e = sbuf[t] - val;  // exclusive
        bucketOfs[t] = e;
        bucketFill[t] = e;
    }
    if (t == 0) row_ptr[N] = (unsigned)ET;
}

// ---------------- bucket -> per-node CSR scatter (+ row_ptr build) ----------

__global__ __launch_bounds__(256) void k_sort(const unsigned* __restrict__ pairs,
                                              const unsigned* __restrict__ bucketOfs,
                                              const unsigned* __restrict__ bucketCnt,
                                              unsigned* __restrict__ row_ptr,
                                              unsigned* __restrict__ ssrc,
                                              int N, int shift) {
    __shared__ unsigned f[1024];      // counts -> cursors
    __shared__ unsigned part[256];
    const int b = blockIdx.x;
    const int t = threadIdx.x;
    const int nodes = 1 << shift;     // <= 1024
    const int bbase = b << shift;
    for (int i = t; i < 1024; i += 256) f[i] = 0u;
    __syncthreads();
    const unsigned base = bucketOfs[b];
    const unsigned cnt = bucketCnt[b];
    // pass 1: per-node degree count
    for (unsigned i = (unsigned)t; i < cnt; i += 256u)
        atomicAdd(&f[pairs[base + i] >> 20], 1u);
    __syncthreads();
    // block exclusive scan over 1024 entries (4 per thread)
    unsigned a0 = f[4 * t + 0], a1 = f[4 * t + 1];
    unsigned a2 = f[4 * t + 2], a3 = f[4 * t + 3];
    unsigned ssum = a0 + a1 + a2 + a3;
    part[t] = ssum;
    __syncthreads();
    for (int off = 1; off < 256; off <<= 1) {
        unsigned add = (t >= off) ? part[t - off] : 0u;
        __syncthreads();
        part[t] += add;
        __syncthreads();
    }
    unsigned excl = part[t] - ssum;
    unsigned c0 = base + excl;
    unsigned c1 = c0 + a0;
    unsigned c2 = c1 + a1;
    unsigned c3 = c2 + a2;
    {
        int v0 = bbase + 4 * t;
        if (v0 + 0 < N && 4 * t + 0 < nodes) row_ptr[v0 + 0] = c0;
        if (v0 + 1 < N && 4 * t + 1 < nodes) row_ptr[v0 + 1] = c1;
        if (v0 + 2 < N && 4 * t + 2 < nodes) row_ptr[v0 + 2] = c2;
        if (v0 + 3 < N && 4 * t + 3 < nodes) row_ptr[v0 + 3] = c3;
    }
    f[4 * t + 0] = c0;
    f[4 * t + 1] = c1;
    f[4 * t + 2] = c2;
    f[4 * t + 3] = c3;
    __syncthreads();
    // pass 2: scatter
    for (unsigned i = (unsigned)t; i < cnt; i += 256u) {
        unsigned pk = pairs[base + i];
        unsigned local = pk >> 20;
        unsigned pos = atomicAdd(&f[local], 1u);
        ssrc[pos] = pk & 0xFFFFFu;
    }
}

// ---------------- layer-1 aggregation: one wave per dst node ----------------
// Two-phase batched; a_s1 is fp16 (1.6 MB, L2-resident -> gather is L2 hit).

__global__ __launch_bounds__(256) void k_agg1(const unsigned short* __restrict__ h1b,
                                              const __half* __restrict__ a_s1,
                                              const float* __restrict__ a_d1,
                                              const float* __restrict__ b1,
                                              const unsigned* __restrict__ row_ptr,
                                              const unsigned* __restrict__ ssrc,
                                              float* __restrict__ g, int N) {
    int wid = threadIdx.x >> 6, lane = threadIdx.x & 63;
    int v = blockIdx.x * 4 + wid;
    if (v >= N) return;
    unsigned base = row_ptr[v];
    unsigned deg = row_ptr[v + 1] - base;

    const int eA = lane >> 3, hA = lane & 7;      // phase-A mapping
    float adv = a_d1[(size_t)v * 8 + hA];
    const int half = lane >> 5, j32 = lane & 31;  // phase-B mapping
    const int hq = j32 >> 2;                      // head of channel pair

    float denom = 0.f, acc0 = 0.f, acc1 = 0.f;
    for (unsigned jj = 0; jj < deg; jj += 8) {
        // ---- phase A: attention for 8 edges (one (e,h) per lane) ----
        unsigned ee = jj + (unsigned)eA;
        bool val = ee < deg;
        unsigned sL = ssrc[base + (val ? ee : 0u)];
        float as = __half2float(a_s1[(size_t)sL * 8 + hA]);
        float eatt = as + adv;
        eatt = eatt > 0.f ? eatt : NEG_SLOPE * eatt;
        float p = val ? __expf(eatt) : 0.f;
        denom += p;
        // ---- phase B: accumulate 8 edges, 2 per iter (one per half-wave) ----
#pragma unroll
        for (int k = 0; k < 4; k++) {
            int esel = k * 2 + half;
            unsigned s_my = (unsigned)__shfl((int)sL, esel * 8);
            float p_my = __shfl(p, esel * 8 + hq);
            unsigned u = *(const unsigned*)(h1b + ((size_t)s_my << 6) + (j32 << 1));
            float lo = __uint_as_float(u << 16);
            float hi = __uint_as_float(u & 0xffff0000u);
            acc0 = fmaf(lo, p_my, acc0);
            acc1 = fmaf(hi, p_my, acc1);
        }
    }
    // cross-half edge-subset reduce
    acc0 += __shfl_xor(acc0, 32);
    acc1 += __shfl_xor(acc1, 32);
    // denom: sum over e (lanes at stride 8)
    denom += __shfl_xor(denom, 8);
    denom += __shfl_xor(denom, 16);
    denom += __shfl_xor(denom, 32);
    float dn = __shfl(denom, hq);   // denom for my channel pair's head
    if (half == 0) {
        float inv = 1.0f / dn;
        int c0 = j32 * 2;
        float t0 = acc0 * inv + b1[c0];
        float t1 = acc1 * inv + b1[c0 + 1];
        t0 = t0 > 0.f ? t0 : (__expf(t0) - 1.f);
        t1 = t1 > 0.f ? t1 : (__expf(t1) - 1.f);
        *(float2*)&g[(size_t)v * F1 + c0] = make_float2(t0, t1);
    }
}

// ---------------- GEMM2 + attention dots layer 2 ----------------
// h2 stored as fp16 (3.2 MB, L2-resident for agg2's gather).

__global__ __launch_bounds__(256) void k_gemm2(const float* __restrict__ g,
                                               const float* __restrict__ W2,
                                               const float* __restrict__ as2w,
                                               const float* __restrict__ ad2w,
                                               __half* __restrict__ h2,
                                               float* __restrict__ a_s2,
                                               float* __restrict__ a_d2, int N) {
    __shared__ float W2s[F1][NCLS];
    int tid = threadIdx.x;
    for (int i = tid; i < F1 * NCLS; i += 256) ((float*)W2s)[i] = W2[i];
    __syncthreads();
    int lane = tid & 63, wid = tid >> 6;
    int n = blockIdx.x * 16 + wid * 4 + (lane >> 4);
    int c = lane & 15;
    if (n >= N) return;
    float acc = 0.f;
#pragma unroll
    for (int k4 = 0; k4 < 16; k4++) {
        float4 gv = *(const float4*)(g + (size_t)n * F1 + k4 * 4);
        acc = fmaf(gv.x, W2s[k4 * 4 + 0][c], acc);
        acc = fmaf(gv.y, W2s[k4 * 4 + 1][c], acc);
        acc = fmaf(gv.z, W2s[k4 * 4 + 2][c], acc);
        acc = fmaf(gv.w, W2s[k4 * 4 + 3][c], acc);
    }
    h2[(size_t)n * NCLS + c] = __float2half_rn(acc);
    float s = acc * as2w[c];
    float d = acc * ad2w[c];
    s += __shfl_xor(s, 1); s += __shfl_xor(s, 2); s += __shfl_xor(s, 4); s += __shfl_xor(s, 8);
    d += __shfl_xor(d, 1); d += __shfl_xor(d, 2); d += __shfl_xor(d, 4); d += __shfl_xor(d, 8);
    if (c == 0) { a_s2[n] = s; a_d2[n] = d; }
}

// ---------------- layer-2 aggregation (single-pass) -> fp32 output ----------

__global__ __launch_bounds__(256) void k_agg2(const __half* __restrict__ h2,
                                              const float* __restrict__ a_s2,
                                              const float* __restrict__ a_d2,
                                              const float* __restrict__ b2,
                                              const unsigned* __restrict__ row_ptr,
                                              const unsigned* __restrict__ ssrc,
                                              float* __restrict__ out, int N) {
    int wid = threadIdx.x >> 6, lane = threadIdx.x & 63;
    int v = blockIdx.x * 4 + wid;
    if (v >= N) return;
    unsigned base = row_ptr[v];
    unsigned deg = row_ptr[v + 1] - base;
    float adv = a_d2[v];
    int sub = lane >> 4, c = lane & 15;

    float denom = 0.f, acc = 0.f;
    unsigned j = sub;
    for (; j + 12 < deg; j += 16) {
        unsigned s0 = ssrc[base + j + 0];
        unsigned s1 = ssrc[base + j + 4];
        unsigned s2 = ssrc[base + j + 8];
        unsigned s3 = ssrc[base + j + 12];
        float as0 = a_s2[s0];
        float as1 = a_s2[s1];
        float as2 = a_s2[s2];
        float as3 = a_s2[s3];
        float h0 = __half2float(h2[(size_t)s0 * NCLS + c]);
        float h1v = __half2float(h2[(size_t)s1 * NCLS + c]);
        float h2v = __half2float(h2[(size_t)s2 * NCLS + c]);
        float h3 = __half2float(h2[(size_t)s3 * NCLS + c]);
        float e0 = as0 + adv; e0 = e0 > 0.f ? e0 : NEG_SLOPE * e0; float p0 = __expf(e0);
        float e1 = as1 + adv; e1 = e1 > 0.f ? e1 : NEG_SLOPE * e1; float p1 = __expf(e1);
        float e2 = as2 + adv; e2 = e2 > 0.f ? e2 : NEG_SLOPE * e2; float p2 = __expf(e2);
        float e3 = as3 + adv; e3 = e3 > 0.f ? e3 : NEG_SLOPE * e3; float p3 = __expf(e3);
        denom += (p0 + p1) + (p2 + p3);
        acc = fmaf(h0, p0, acc);
        acc = fmaf(h1v, p1, acc);
        acc = fmaf(h2v, p2, acc);
        acc = fmaf(h3, p3, acc);
    }
    for (; j < deg; j += 4) {
        unsigned s = ssrc[base + j];
        float as = a_s2[s];
        float hv = __half2float(h2[(size_t)s * NCLS + c]);
        float e = as + adv; e = e > 0.f ? e : NEG_SLOPE * e;
        float p = __expf(e);
        denom += p;
        acc = fmaf(hv, p, acc);
    }
    acc += __shfl_xor(acc, 16);
    acc += __shfl_xor(acc, 32);
    denom += __shfl_xor(denom, 16);
    denom += __shfl_xor(denom, 32);
    if (lane < 16) {
        out[(size_t)v * NCLS + c] = acc * (1.0f / denom) + b2[c];
    }
}

// ---------------- launch ----------------

static inline size_t algn(size_t x) { return (x + 255) & ~(size_t)255; }

extern "C" void kernel_launch(void* const* d_in, const int* in_sizes, int n_in,
                              void* d_out, int out_size, void* d_ws, size_t ws_size,
                              hipStream_t stream) {
    const float* x   = (const float*)d_in[0];
    const int* ei    = (const int*)d_in[1];
    const float* W1  = (const float*)d_in[2];
    const float* as1 = (const float*)d_in[3];
    const float* ad1 = (const float*)d_in[4];
    const float* b1  = (const float*)d_in[5];
    const float* W2  = (const float*)d_in[6];
    const float* as2 = (const float*)d_in[7];
    const float* ad2 = (const float*)d_in[8];
    const float* b2  = (const float*)d_in[9];

    const int N = in_sizes[0] / F_IN;
    const int E = in_sizes[1] / 2;
    const int ET = E + N;

    // coarse buckets for the CSR sort (nodes-per-bucket = 1<<shift, nb <= 1024)
    int shift = 8;
    int nb = (N + 255) >> 8;
    while (nb > 1024) { shift++; nb = (N + (1 << shift) - 1) >> shift; }

    const int GA_T = ((N / 2) + 63) / 64;       // gemm tiles in half A
    const int rowSplit = GA_T * 64;
    const int GB_T = (N - rowSplit + 63) / 64;  // gemm tiles in half B

    char* p = (char*)d_ws;
    unsigned short* h1b = (unsigned short*)p;  p += algn((size_t)N * F1 * 2);
    float* g    = (float*)p;      p += algn((size_t)N * F1 * 4);
    __half* a_s1 = (__half*)p;    p += algn((size_t)N * 8 * 2);
    float* a_d1 = (float*)p;      p += algn((size_t)N * 8 * 4);
    __half* h2  = (__half*)p;     p += algn((size_t)N * NCLS * 2);
    float* a_s2 = (float*)p;      p += algn((size_t)N * 4);
    float* a_d2 = (float*)p;      p += algn((size_t)N * 4);
    unsigned* row_ptr = (unsigned*)p;  p += algn((size_t)(N + 1) * 4);
    unsigned* bucketCnt  = (unsigned*)p;  p += algn((size_t)1024 * 4);
    unsigned* bucketOfs  = (unsigned*)p;  p += algn((size_t)1024 * 4);
    unsigned* bucketFill = (unsigned*)p;  p += algn((size_t)1024 * 4);
    unsigned* mode    = (unsigned*)p;  p += algn(256);
    unsigned short* W1T = (unsigned short*)p;  p += algn((size_t)F_IN * F1 * 2);
    unsigned* ssrc = (unsigned*)p;     p += algn((size_t)ET * 4);
    // pairs[] lifetime (fusedB -> k_sort) is disjoint from g[] (agg1 -> gemm2):
    // alias to save workspace. ET*4 (13.2 MB) <= N*F1*4 (25.6 MB).
    unsigned* pairs = (unsigned*)g;

    hipMemsetAsync(bucketCnt, 0, (size_t)nb * 4, stream);

    dim3 b256(256);
    k_detect<<<dim3(1), dim3(64), 0, stream>>>(ei, E, mode);
    k_prep<<<dim3((F_IN * F1 + 255) / 256), b256, 0, stream>>>(W1, W1T);

    // A: gemm rows [0,rowSplit) interleaved with edge decode + bucket hist
    k_fusedA<<<dim3(2 * GA_T), b256, 0, stream>>>(x, W1T, as1, ad1, h1b, a_s1, a_d1, N,
                                                  ei, mode, bucketCnt,
                                                  E, ET, GA_T, nb, shift);

    k_scan_buckets<<<dim3(1), dim3(1024), 0, stream>>>(bucketCnt, nb, ET, bucketOfs,
                                                       bucketFill, row_ptr, N);

    // B: gemm rows [rowSplit,N) interleaved with bucket scatter
    k_fusedB<<<dim3(2 * GB_T), b256, 0, stream>>>(x, W1T, as1, ad1, h1b, a_s1, a_d1, N,
                                                  rowSplit, ei, mode, bucketFill,
                                                  pairs, E, ET, GB_T, nb, shift);

    // bucket -> per-node CSR (builds row_ptr + ssrc)
    k_sort<<<dim3(nb), b256, 0, stream>>>(pairs, bucketOfs, bucketCnt, row_ptr, ssrc, N, shift);

    k_agg1<<<dim3((N + 3) / 4), b256, 0, stream>>>(h1b, a_s1, a_d1, b1, row_ptr, ssrc, g, N);
    k_gemm2<<<dim3((N + 15) / 16), b256, 0, stream>>>(g, W2, as2, ad2, h2, a_s2, a_d2, N);
    k_agg2<<<dim3((N + 3) / 4), b256, 0, stream>>>(h2, a_s2, a_d2, b2, row_ptr, ssrc,
                                                   (float*)d_out, N);
}

// Round 7
// 571.408 us; speedup vs baseline: 1.3500x; 1.0443x over previous
//
#include <hip/hip_runtime.h>
#include <hip/hip_fp16.h>

// Problem constants (from reference setup_inputs)
#define F_IN 512
#define F1 64          // HEADS*HID = 8*8
#define NCLS 16
#define NEG_SLOPE 0.2f
#define NS 256         // edge-path blocks per fused kernel

typedef __attribute__((ext_vector_type(8))) short short8;
typedef __attribute__((ext_vector_type(4))) float f32x4;

__device__ __forceinline__ unsigned short f2bf(float f) {
    unsigned u = __float_as_uint(f);
    return (unsigned short)((u + 0x7fffu + ((u >> 16) & 1u)) >> 16);
}
__device__ __forceinline__ float bf2f(unsigned short u) {
    return __uint_as_float(((unsigned)u) << 16);
}

// ---------------- edge decode (int32 vs int64 robust) ----------------

__global__ __launch_bounds__(64) void k_detect(const int* __restrict__ ei, int E,
                                               unsigned* __restrict__ mode) {
    int t = threadIdx.x;
    unsigned nz = 0;
    int lim = (E > 256) ? 256 : E;
    for (int k = t; k < lim; k += 64) nz |= (unsigned)ei[2 * k + 1];
    for (int off = 1; off < 64; off <<= 1) nz |= __shfl_xor(nz, off);
    if (t == 0) *mode = (nz == 0) ? 1u : 0u;   // 1 = int64 layout
}

__device__ __forceinline__ void decode_edge(const int* __restrict__ ei,
                                            const long long* __restrict__ e64,
                                            bool m64, unsigned i, int E, int N,
                                            int& s, int& v) {
    if (i < (unsigned)E) {
        if (m64) { s = (int)e64[i]; v = (int)e64[E + i]; }
        else     { s = ei[i];       v = ei[E + i]; }
    } else {
        s = (int)(i - (unsigned)E);
        v = s;
    }
    s = s < 0 ? 0 : (s >= N ? N - 1 : s);
    v = v < 0 ? 0 : (v >= N ? N - 1 : v);
}

__device__ __forceinline__ int decode_dst(const int* __restrict__ ei,
                                          const long long* __restrict__ e64,
                                          bool m64, unsigned i, int E, int N) {
    int v;
    if (i < (unsigned)E) v = m64 ? (int)e64[E + i] : ei[E + i];
    else                 v = (int)(i - (unsigned)E);
    return v < 0 ? 0 : (v >= N ? N - 1 : v);
}

// ---------------- W1 pre-convert: fp32 [512][64] -> bf16 transposed [64][512]

__global__ __launch_bounds__(256) void k_prep(const float* __restrict__ W1,
                                              unsigned short* __restrict__ W1T) {
    int t = blockIdx.x * 256 + threadIdx.x;
    if (t < F_IN * F1) {
        int k = t >> 6, c = t & 63;
        W1T[(size_t)c * F_IN + k] = f2bf(W1[t]);
    }
}

// ---------------- GEMM1 MFMA tile (bf16 in, fp32 acc) ----------------
// Barrier-free: NO LDS. Each wave owns a 16x64 tile. A fragment = 32 B of the
// lane's own x row (fp32->bf16 in-reg); B fragment = contiguous 16 B of W1T
// (64 KB total, L1/L2-hot across all blocks). unroll 4 k-steps for MLP.
// Fragment layouts per guide §3: A[m=lane&15][k=quad*8+j];
// B[k=quad*8+j][n=lane&15]; C/D col=lane&15, row=quad*4+reg.

__device__ __forceinline__ void gemm1_tile(const float* __restrict__ x,
                                           const unsigned short* __restrict__ W1T,
                                           const float* __restrict__ att_s,
                                           const float* __restrict__ att_d,
                                           unsigned short* __restrict__ h1b,
                                           __half* __restrict__ a_s1,
                                           float* __restrict__ a_d1,
                                           int N, int row0) {
    const int tid = threadIdx.x;
    const int w = tid >> 6, lane = tid & 63;
    const int quad = lane >> 4, r16 = lane & 15;

    f32x4 acc[4];
#pragma unroll
    for (int t = 0; t < 4; t++) acc[t] = (f32x4){0.f, 0.f, 0.f, 0.f};

    const int arow = row0 + w * 16 + r16;   // this lane's A row
    const bool rok = arow < N;
    const float* xrow = x + (size_t)arow * F_IN + quad * 8;
    const unsigned short* wbase = W1T + quad * 8;

#pragma unroll 4
    for (int k0 = 0; k0 < F_IN; k0 += 32) {
        short8 af;
        {
            float4 v0 = make_float4(0.f, 0.f, 0.f, 0.f), v1 = v0;
            if (rok) {
                v0 = *(const float4*)(xrow + k0);
                v1 = *(const float4*)(xrow + k0 + 4);
            }
            af[0] = (short)f2bf(v0.x); af[1] = (short)f2bf(v0.y);
            af[2] = (short)f2bf(v0.z); af[3] = (short)f2bf(v0.w);
            af[4] = (short)f2bf(v1.x); af[5] = (short)f2bf(v1.y);
            af[6] = (short)f2bf(v1.z); af[7] = (short)f2bf(v1.w);
        }
#pragma unroll
        for (int t = 0; t < 4; t++) {
            short8 bf = *(const short8*)(wbase + (size_t)(t * 16 + r16) * F_IN + k0);
            acc[t] = __builtin_amdgcn_mfma_f32_16x16x32_bf16(af, bf, acc[t], 0, 0, 0);
        }
    }

    // epilogue
    float ats[4], atd[4];
#pragma unroll
    for (int t = 0; t < 4; t++) {
        ats[t] = att_s[t * 16 + r16];
        atd[t] = att_d[t * 16 + r16];
    }
#pragma unroll
    for (int r = 0; r < 4; r++) {
        int grow = row0 + w * 16 + quad * 4 + r;
        bool ok = grow < N;
        float ps[4], pd[4];
#pragma unroll
        for (int t = 0; t < 4; t++) {
            float vv = acc[t][r];
            if (ok) h1b[(size_t)grow * F1 + t * 16 + r16] = f2bf(vv);
            ps[t] = vv * ats[t];
            pd[t] = vv * atd[t];
        }
#pragma unroll
        for (int t = 0; t < 4; t++) {
            ps[t] += __shfl_xor(ps[t], 1); pd[t] += __shfl_xor(pd[t], 1);
            ps[t] += __shfl_xor(ps[t], 2); pd[t] += __shfl_xor(pd[t], 2);
            ps[t] += __shfl_xor(ps[t], 4); pd[t] += __shfl_xor(pd[t], 4);
        }
        if (ok && (r16 & 7) == 0) {
            int hh0 = r16 >> 3;   // 0 or 1
#pragma unroll
            for (int t = 0; t < 4; t++) {
                a_s1[(size_t)grow * 8 + t * 2 + hh0] = __float2half_rn(ps[t]);
                a_d1[(size_t)grow * 8 + t * 2 + hh0] = pd[t];
            }
        }
    }
}

// ---------------- fused A: bucket histogram (b<NS) || gemm1 rows [0,rowSplit)

__global__ __launch_bounds__(256) void k_fusedA(const float* __restrict__ x,
                                                const unsigned short* __restrict__ W1T,
                                                const float* __restrict__ att_s,
                                                const float* __restrict__ att_d,
                                                unsigned short* __restrict__ h1b,
                                                __half* __restrict__ a_s1,
                                                float* __restrict__ a_d1, int N,
                                                const int* __restrict__ ei,
                                                const unsigned* __restrict__ mode,
                                                unsigned* __restrict__ bucketCnt,
                                                int E, int ET,
                                                int nb, int shift) {
    __shared__ unsigned cntL[1024];
    unsigned b = blockIdx.x;
    if (b >= NS) {
        gemm1_tile(x, W1T, att_s, att_d, h1b, a_s1, a_d1, N, (int)(b - NS) * 64);
        return;
    }
    for (int i = threadIdx.x; i < 1024; i += 256) cntL[i] = 0u;
    __syncthreads();

    const int chunk = (ET + NS - 1) / NS;
    const int cbase = (int)b * chunk;
    const int cend = (cbase + chunk < ET) ? cbase + chunk : ET;
    bool m64 = (*mode != 0u);
    const long long* e64 = (const long long*)ei;
    int i = cbase + threadIdx.x;
    for (; i + 768 < cend; i += 1024) {
        int v0 = decode_dst(ei, e64, m64, (unsigned)i, E, N);
        int v1 = decode_dst(ei, e64, m64, (unsigned)(i + 256), E, N);
        int v2 = decode_dst(ei, e64, m64, (unsigned)(i + 512), E, N);
        int v3 = decode_dst(ei, e64, m64, (unsigned)(i + 768), E, N);
        atomicAdd(&cntL[(unsigned)v0 >> shift], 1u);
        atomicAdd(&cntL[(unsigned)v1 >> shift], 1u);
        atomicAdd(&cntL[(unsigned)v2 >> shift], 1u);
        atomicAdd(&cntL[(unsigned)v3 >> shift], 1u);
    }
    for (; i < cend; i += 256) {
        int v = decode_dst(ei, e64, m64, (unsigned)i, E, N);
        atomicAdd(&cntL[(unsigned)v >> shift], 1u);
    }
    __syncthreads();
    for (int k = threadIdx.x; k < nb; k += 256) {
        unsigned c = cntL[k];
        if (c) atomicAdd(&bucketCnt[k], c);
    }
}

// ---------------- fused B: bucket scatter (b<NS) || gemm1 rows [rowSplit,N) --
// Scatter: big contiguous chunks (ET/NS ~ 13K edges) so each (block,bucket)
// private span is ~130 B -> near-full-line writebacks (was 43 B spans at 4x
// write amplification with per-gemm-tile chunking).

__global__ __launch_bounds__(256) void k_fusedB(const float* __restrict__ x,
                                                const unsigned short* __restrict__ W1T,
                                                const float* __restrict__ att_s,
                                                const float* __restrict__ att_d,
                                                unsigned short* __restrict__ h1b,
                                                __half* __restrict__ a_s1,
                                                float* __restrict__ a_d1, int N,
                                                int rowSplit,
                                                const int* __restrict__ ei,
                                                const unsigned* __restrict__ mode,
                                                unsigned* __restrict__ bucketFill,
                                                unsigned* __restrict__ pairs,
                                                int E, int ET,
                                                int nb, int shift) {
    __shared__ unsigned cntA[1024];   // counts -> span delta
    __shared__ unsigned ofsA[1024];   // local excl ofs -> cursor
    __shared__ unsigned part[256];
    unsigned b = blockIdx.x;
    if (b >= NS) {
        gemm1_tile(x, W1T, att_s, att_d, h1b, a_s1, a_d1, N,
                   rowSplit + (int)(b - NS) * 64);
        return;
    }
    const int t = threadIdx.x;
    const int chunk = (ET + NS - 1) / NS;
    const int cbase = (int)b * chunk;
    const int cend = (cbase + chunk < ET) ? cbase + chunk : ET;
    const unsigned lmask = (1u << shift) - 1u;
    bool m64 = (*mode != 0u);
    const long long* e64 = (const long long*)ei;

    for (int k = t; k < 1024; k += 256) cntA[k] = 0u;
    __syncthreads();
    // phase 1: count (decode dst only)
    for (int k = cbase + t; k < cend; k += 256) {
        int v = decode_dst(ei, e64, m64, (unsigned)k, E, N);
        atomicAdd(&cntA[(unsigned)v >> shift], 1u);
    }
    __syncthreads();
    // exclusive scan over 1024 entries (4 per thread)
    unsigned a0 = cntA[4 * t + 0], a1 = cntA[4 * t + 1];
    unsigned a2 = cntA[4 * t + 2], a3 = cntA[4 * t + 3];
    unsigned ssum = a0 + a1 + a2 + a3;
    part[t] = ssum;
    __syncthreads();
    for (int off = 1; off < 256; off <<= 1) {
        unsigned add = (t >= off) ? part[t - off] : 0u;
        __syncthreads();
        part[t] += add;
        __syncthreads();
    }
    unsigned excl = part[t] - ssum;
    ofsA[4 * t + 0] = excl;
    ofsA[4 * t + 1] = excl + a0;
    ofsA[4 * t + 2] = excl + a0 + a1;
    ofsA[4 * t + 3] = excl + a0 + a1 + a2;
    __syncthreads();
    // reserve private global spans; cntA becomes delta = globalBase - localOfs
    for (int k = t; k < nb; k += 256) {
        unsigned c = cntA[k];
        unsigned g = c ? atomicAdd(&bucketFill[k], c) : 0u;
        cntA[k] = g - ofsA[k];
    }
    __syncthreads();
    // phase 2: re-decode and scatter packed records into private spans
    for (int k = cbase + t; k < cend; k += 256) {
        int s, v;
        decode_edge(ei, e64, m64, (unsigned)k, E, N, s, v);
        unsigned bb = (unsigned)v >> shift;
        unsigned slot = atomicAdd(&ofsA[bb], 1u);
        pairs[cntA[bb] + slot] = (unsigned)s | (((unsigned)v & lmask) << 20);
    }
}

// ---------------- bucket scan (global CSR offsets at bucket granularity) ----

__global__ __launch_bounds__(1024) void k_scan_buckets(const unsigned* __restrict__ bucketCnt,
                                                       int nb, int ET,
                                                       unsigned* __restrict__ bucketOfs,
                                                       unsigned* __restrict__ bucketFill,
                                                       unsigned* __restrict__ row_ptr,
                                                       int N) {
    __shared__ unsigned sbuf[1024];
    int t = threadIdx.x;
    unsigned val = (t < nb) ? bucketCnt[t] : 0u;
    sbuf[t] = val;
    __syncthreads();
    for (int off = 1; off < 1024; off <<= 1) {
        unsigned add = (t >= off) ? sbuf[t - off] : 0u;
        __syncthreads();
        sbuf[t] += add;
        __syncthreads();
    }
    if (t < nb) {
        unsigned e = sbuf[t] - val;  // exclusive
        bucketOfs[t] = e;
        bucketFill[t] = e;
    }
    if (t == 0) row_ptr[N] = (unsigned)ET;
}

// ---------------- bucket -> per-node CSR scatter (+ row_ptr build) ----------

__global__ __launch_bounds__(256) void k_sort(const unsigned* __restrict__ pairs,
                                              const unsigned* __restrict__ bucketOfs,
                                              const unsigned* __restrict__ bucketCnt,
                                              unsigned* __restrict__ row_ptr,
                                              unsigned* __restrict__ ssrc,
                                              int N, int shift) {
    __shared__ unsigned f[1024];      // counts -> cursors
    __shared__ unsigned part[256];
    const int b = blockIdx.x;
    const int t = threadIdx.x;
    const int nodes = 1 << shift;     // <= 1024
    const int bbase = b << shift;
    for (int i = t; i < 1024; i += 256) f[i] = 0u;
    __syncthreads();
    const unsigned base = bucketOfs[b];
    const unsigned cnt = bucketCnt[b];
    // pass 1: per-node degree count
    for (unsigned i = (unsigned)t; i < cnt; i += 256u)
        atomicAdd(&f[pairs[base + i] >> 20], 1u);
    __syncthreads();
    // block exclusive scan over 1024 entries (4 per thread)
    unsigned a0 = f[4 * t + 0], a1 = f[4 * t + 1];
    unsigned a2 = f[4 * t + 2], a3 = f[4 * t + 3];
    unsigned ssum = a0 + a1 + a2 + a3;
    part[t] = ssum;
    __syncthreads();
    for (int off = 1; off < 256; off <<= 1) {
        unsigned add = (t >= off) ? part[t - off] : 0u;
        __syncthreads();
        part[t] += add;
        __syncthreads();
    }
    unsigned excl = part[t] - ssum;
    unsigned c0 = base + excl;
    unsigned c1 = c0 + a0;
    unsigned c2 = c1 + a1;
    unsigned c3 = c2 + a2;
    {
        int v0 = bbase + 4 * t;
        if (v0 + 0 < N && 4 * t + 0 < nodes) row_ptr[v0 + 0] = c0;
        if (v0 + 1 < N && 4 * t + 1 < nodes) row_ptr[v0 + 1] = c1;
        if (v0 + 2 < N && 4 * t + 2 < nodes) row_ptr[v0 + 2] = c2;
        if (v0 + 3 < N && 4 * t + 3 < nodes) row_ptr[v0 + 3] = c3;
    }
    f[4 * t + 0] = c0;
    f[4 * t + 1] = c1;
    f[4 * t + 2] = c2;
    f[4 * t + 3] = c3;
    __syncthreads();
    // pass 2: scatter
    for (unsigned i = (unsigned)t; i < cnt; i += 256u) {
        unsigned pk = pairs[base + i];
        unsigned local = pk >> 20;
        unsigned pos = atomicAdd(&f[local], 1u);
        ssrc[pos] = pk & 0xFFFFFu;
    }
}

// ---------------- layer-1 aggregation: one wave per dst node ----------------
// Two-phase batched; a_s1 is fp16 (1.6 MB, L2-resident -> gather is L2 hit).

__global__ __launch_bounds__(256) void k_agg1(const unsigned short* __restrict__ h1b,
                                              const __half* __restrict__ a_s1,
                                              const float* __restrict__ a_d1,
                                              const float* __restrict__ b1,
                                              const unsigned* __restrict__ row_ptr,
                                              const unsigned* __restrict__ ssrc,
                                              float* __restrict__ g, int N) {
    int wid = threadIdx.x >> 6, lane = threadIdx.x & 63;
    int v = blockIdx.x * 4 + wid;
    if (v >= N) return;
    unsigned base = row_ptr[v];
    unsigned deg = row_ptr[v + 1] - base;

    const int eA = lane >> 3, hA = lane & 7;      // phase-A mapping
    float adv = a_d1[(size_t)v * 8 + hA];
    const int half = lane >> 5, j32 = lane & 31;  // phase-B mapping
    const int hq = j32 >> 2;                      // head of channel pair

    float denom = 0.f, acc0 = 0.f, acc1 = 0.f;
    for (unsigned jj = 0; jj < deg; jj += 8) {
        // ---- phase A: attention for 8 edges (one (e,h) per lane) ----
        unsigned ee = jj + (unsigned)eA;
        bool val = ee < deg;
        unsigned sL = ssrc[base + (val ? ee : 0u)];
        float as = __half2float(a_s1[(size_t)sL * 8 + hA]);
        float eatt = as + adv;
        eatt = eatt > 0.f ? eatt : NEG_SLOPE * eatt;
        float p = val ? __expf(eatt) : 0.f;
        denom += p;
        // ---- phase B: accumulate 8 edges, 2 per iter (one per half-wave) ----
#pragma unroll
        for (int k = 0; k < 4; k++) {
            int esel = k * 2 + half;
            unsigned s_my = (unsigned)__shfl((int)sL, esel * 8);
            float p_my = __shfl(p, esel * 8 + hq);
            unsigned u = *(const unsigned*)(h1b + ((size_t)s_my << 6) + (j32 << 1));
            float lo = __uint_as_float(u << 16);
            float hi = __uint_as_float(u & 0xffff0000u);
            acc0 = fmaf(lo, p_my, acc0);
            acc1 = fmaf(hi, p_my, acc1);
        }
    }
    // cross-half edge-subset reduce
    acc0 += __shfl_xor(acc0, 32);
    acc1 += __shfl_xor(acc1, 32);
    // denom: sum over e (lanes at stride 8)
    denom += __shfl_xor(denom, 8);
    denom += __shfl_xor(denom, 16);
    denom += __shfl_xor(denom, 32);
    float dn = __shfl(denom, hq);   // denom for my channel pair's head
    if (half == 0) {
        float inv = 1.0f / dn;
        int c0 = j32 * 2;
        float t0 = acc0 * inv + b1[c0];
        float t1 = acc1 * inv + b1[c0 + 1];
        t0 = t0 > 0.f ? t0 : (__expf(t0) - 1.f);
        t1 = t1 > 0.f ? t1 : (__expf(t1) - 1.f);
        *(float2*)&g[(size_t)v * F1 + c0] = make_float2(t0, t1);
    }
}

// ---------------- GEMM2 + attention dots layer 2 ----------------
// h2 stored as fp16 (3.2 MB, L2-resident for agg2's gather).

__global__ __launch_bounds__(256) void k_gemm2(const float* __restrict__ g,
                                               const float* __restrict__ W2,
                                               const float* __restrict__ as2w,
                                               const float* __restrict__ ad2w,
                                               __half* __restrict__ h2,
                                               float* __restrict__ a_s2,
                                               float* __restrict__ a_d2, int N) {
    __shared__ float W2s[F1][NCLS];
    int tid = threadIdx.x;
    for (int i = tid; i < F1 * NCLS; i += 256) ((float*)W2s)[i] = W2[i];
    __syncthreads();
    int lane = tid & 63, wid = tid >> 6;
    int n = blockIdx.x * 16 + wid * 4 + (lane >> 4);
    int c = lane & 15;
    if (n >= N) return;
    float acc = 0.f;
#pragma unroll
    for (int k4 = 0; k4 < 16; k4++) {
        float4 gv = *(const float4*)(g + (size_t)n * F1 + k4 * 4);
        acc = fmaf(gv.x, W2s[k4 * 4 + 0][c], acc);
        acc = fmaf(gv.y, W2s[k4 * 4 + 1][c], acc);
        acc = fmaf(gv.z, W2s[k4 * 4 + 2][c], acc);
        acc = fmaf(gv.w, W2s[k4 * 4 + 3][c], acc);
    }
    h2[(size_t)n * NCLS + c] = __float2half_rn(acc);
    float s = acc * as2w[c];
    float d = acc * ad2w[c];
    s += __shfl_xor(s, 1); s += __shfl_xor(s, 2); s += __shfl_xor(s, 4); s += __shfl_xor(s, 8);
    d += __shfl_xor(d, 1); d += __shfl_xor(d, 2); d += __shfl_xor(d, 4); d += __shfl_xor(d, 8);
    if (c == 0) { a_s2[n] = s; a_d2[n] = d; }
}

// ---------------- layer-2 aggregation (single-pass) -> fp32 output ----------

__global__ __launch_bounds__(256) void k_agg2(const __half* __restrict__ h2,
                                              const float* __restrict__ a_s2,
                                              const float* __restrict__ a_d2,
                                              const float* __restrict__ b2,
                                              const unsigned* __restrict__ row_ptr,
                                              const unsigned* __restrict__ ssrc,
                                              float* __restrict__ out, int N) {
    int wid = threadIdx.x >> 6, lane = threadIdx.x & 63;
    int v = blockIdx.x * 4 + wid;
    if (v >= N) return;
    unsigned base = row_ptr[v];
    unsigned deg = row_ptr[v + 1] - base;
    float adv = a_d2[v];
    int sub = lane >> 4, c = lane & 15;

    float denom = 0.f, acc = 0.f;
    unsigned j = sub;
    for (; j + 12 < deg; j += 16) {
        unsigned s0 = ssrc[base + j + 0];
        unsigned s1 = ssrc[base + j + 4];
        unsigned s2 = ssrc[base + j + 8];
        unsigned s3 = ssrc[base + j + 12];
        float as0 = a_s2[s0];
        float as1 = a_s2[s1];
        float as2 = a_s2[s2];
        float as3 = a_s2[s3];
        float h0 = __half2float(h2[(size_t)s0 * NCLS + c]);
        float h1v = __half2float(h2[(size_t)s1 * NCLS + c]);
        float h2v = __half2float(h2[(size_t)s2 * NCLS + c]);
        float h3 = __half2float(h2[(size_t)s3 * NCLS + c]);
        float e0 = as0 + adv; e0 = e0 > 0.f ? e0 : NEG_SLOPE * e0; float p0 = __expf(e0);
        float e1 = as1 + adv; e1 = e1 > 0.f ? e1 : NEG_SLOPE * e1; float p1 = __expf(e1);
        float e2 = as2 + adv; e2 = e2 > 0.f ? e2 : NEG_SLOPE * e2; float p2 = __expf(e2);
        float e3 = as3 + adv; e3 = e3 > 0.f ? e3 : NEG_SLOPE * e3; float p3 = __expf(e3);
        denom += (p0 + p1) + (p2 + p3);
        acc = fmaf(h0, p0, acc);
        acc = fmaf(h1v, p1, acc);
        acc = fmaf(h2v, p2, acc);
        acc = fmaf(h3, p3, acc);
    }
    for (; j < deg; j += 4) {
        unsigned s = ssrc[base + j];
        float as = a_s2[s];
        float hv = __half2float(h2[(size_t)s * NCLS + c]);
        float e = as + adv; e = e > 0.f ? e : NEG_SLOPE * e;
        float p = __expf(e);
        denom += p;
        acc = fmaf(hv, p, acc);
    }
    acc += __shfl_xor(acc, 16);
    acc += __shfl_xor(acc, 32);
    denom += __shfl_xor(denom, 16);
    denom += __shfl_xor(denom, 32);
    if (lane < 16) {
        out[(size_t)v * NCLS + c] = acc * (1.0f / denom) + b2[c];
    }
}

// ---------------- launch ----------------

static inline size_t algn(size_t x) { return (x + 255) & ~(size_t)255; }

extern "C" void kernel_launch(void* const* d_in, const int* in_sizes, int n_in,
                              void* d_out, int out_size, void* d_ws, size_t ws_size,
                              hipStream_t stream) {
    const float* x   = (const float*)d_in[0];
    const int* ei    = (const int*)d_in[1];
    const float* W1  = (const float*)d_in[2];
    const float* as1 = (const float*)d_in[3];
    const float* ad1 = (const float*)d_in[4];
    const float* b1  = (const float*)d_in[5];
    const float* W2  = (const float*)d_in[6];
    const float* as2 = (const float*)d_in[7];
    const float* ad2 = (const float*)d_in[8];
    const float* b2  = (const float*)d_in[9];

    const int N = in_sizes[0] / F_IN;
    const int E = in_sizes[1] / 2;
    const int ET = E + N;

    // coarse buckets for the CSR sort (nodes-per-bucket = 1<<shift, nb <= 1024)
    int shift = 8;
    int nb = (N + 255) >> 8;
    while (nb > 1024) { shift++; nb = (N + (1 << shift) - 1) >> shift; }

    const int GA_T = ((N / 2) + 63) / 64;       // gemm tiles in half A
    const int rowSplit = GA_T * 64;
    const int GB_T = (N - rowSplit + 63) / 64;  // gemm tiles in half B

    char* p = (char*)d_ws;
    unsigned short* h1b = (unsigned short*)p;  p += algn((size_t)N * F1 * 2);
    float* g    = (float*)p;      p += algn((size_t)N * F1 * 4);
    __half* a_s1 = (__half*)p;    p += algn((size_t)N * 8 * 2);
    float* a_d1 = (float*)p;      p += algn((size_t)N * 8 * 4);
    __half* h2  = (__half*)p;     p += algn((size_t)N * NCLS * 2);
    float* a_s2 = (float*)p;      p += algn((size_t)N * 4);
    float* a_d2 = (float*)p;      p += algn((size_t)N * 4);
    unsigned* row_ptr = (unsigned*)p;  p += algn((size_t)(N + 1) * 4);
    unsigned* bucketCnt  = (unsigned*)p;  p += algn((size_t)1024 * 4);
    unsigned* bucketOfs  = (unsigned*)p;  p += algn((size_t)1024 * 4);
    unsigned* bucketFill = (unsigned*)p;  p += algn((size_t)1024 * 4);
    unsigned* mode    = (unsigned*)p;  p += algn(256);
    unsigned short* W1T = (unsigned short*)p;  p += algn((size_t)F_IN * F1 * 2);
    unsigned* ssrc = (unsigned*)p;     p += algn((size_t)ET * 4);
    // pairs[] lifetime (fusedB -> k_sort) is disjoint from g[] (agg1 -> gemm2):
    // alias to save workspace. ET*4 (13.2 MB) <= N*F1*4 (25.6 MB).
    unsigned* pairs = (unsigned*)g;

    hipMemsetAsync(bucketCnt, 0, (size_t)nb * 4, stream);

    dim3 b256(256);
    k_detect<<<dim3(1), dim3(64), 0, stream>>>(ei, E, mode);
    k_prep<<<dim3((F_IN * F1 + 255) / 256), b256, 0, stream>>>(W1, W1T);

    // A: bucket hist (NS blocks) + gemm rows [0,rowSplit)
    k_fusedA<<<dim3(NS + GA_T), b256, 0, stream>>>(x, W1T, as1, ad1, h1b, a_s1, a_d1, N,
                                                   ei, mode, bucketCnt,
                                                   E, ET, nb, shift);

    k_scan_buckets<<<dim3(1), dim3(1024), 0, stream>>>(bucketCnt, nb, ET, bucketOfs,
                                                       bucketFill, row_ptr, N);

    // B: bucket scatter (NS blocks) + gemm rows [rowSplit,N)
    k_fusedB<<<dim3(NS + GB_T), b256, 0, stream>>>(x, W1T, as1, ad1, h1b, a_s1, a_d1, N,
                                                   rowSplit, ei, mode, bucketFill,
                                                   pairs, E, ET, nb, shift);

    // bucket -> per-node CSR (builds row_ptr + ssrc)
    k_sort<<<dim3(nb), b256, 0, stream>>>(pairs, bucketOfs, bucketCnt, row_ptr, ssrc, N, shift);

    k_agg1<<<dim3((N + 3) / 4), b256, 0, stream>>>(h1b, a_s1, a_d1, b1, row_ptr, ssrc, g, N);
    k_gemm2<<<dim3((N + 15) / 16), b256, 0, stream>>>(g, W2, as2, ad2, h2, a_s2, a_d2, N);
    k_agg2<<<dim3((N + 3) / 4), b256, 0, stream>>>(h2, a_s2, a_d2, b2, row_ptr, ssrc,
                                                   (float*)d_out, N);
}